// Round 4
// baseline (907.832 us; speedup 1.0000x reference)
//
#include <hip/hip_runtime.h>
#include <hip/hip_bf16.h>

typedef unsigned int u32;
typedef unsigned short u16;
typedef __attribute__((ext_vector_type(8))) short bf16x8;
typedef __attribute__((ext_vector_type(4))) float f32x4;
typedef __attribute__((ext_vector_type(4))) u32 u32x4;
typedef __attribute__((ext_vector_type(2))) u32 u32x2;

__device__ __forceinline__ u16 f2b(float f) {
  u32 x = __builtin_bit_cast(u32, f);
  x = (x + 0x7FFFu + ((x >> 16) & 1u)) >> 16;  // RNE
  return (u16)x;
}
__device__ __forceinline__ float b2f(u16 h) {
  return __builtin_bit_cast(float, ((u32)h) << 16);
}

// ---------- 1. transpose fm (512, 1444) -> fmT (1444, 512) ----------
__global__ void transpose_fm(const float* __restrict__ fm, float* __restrict__ fmT) {
  __shared__ float tile[32][33];
  int pb = blockIdx.x * 32, cb = blockIdx.y * 32;
  int tx = threadIdx.x, ty = threadIdx.y;  // block (32,8)
#pragma unroll
  for (int i = 0; i < 4; ++i) {
    int c = cb + ty + i * 8;
    int p = pb + tx;
    tile[ty + i * 8][tx] = (p < 1444) ? fm[c * 1444 + p] : 0.f;
  }
  __syncthreads();
#pragma unroll
  for (int i = 0; i < 4; ++i) {
    int p = pb + ty + i * 8;
    int c = cb + tx;
    if (p < 1444) fmT[p * 512 + c] = tile[tx][ty + i * 8];
  }
}

// ---------- 2. RoI adaptive max pool -> pooled bf16 [256][25088] ----------
__global__ void roi_pool(const float* __restrict__ fmT,
                         const float* __restrict__ rois,
                         u16* __restrict__ pooled) {
  int n = blockIdx.x;
  int c = blockIdx.y * 256 + threadIdx.x;  // 0..511
  const float* rp = rois + n * 4;
  int y0 = (int)(rp[0] * 0.0625f);
  int x0 = (int)(rp[1] * 0.0625f);
  int y2 = (int)(rp[2] * 0.0625f);
  int x2 = (int)(rp[3] * 0.0625f);
  int h = y2 - y0 + 1;
  int w = x2 - x0 + 1;
  int hsA[7], hlA[7], wsA[7], wlA[7];
#pragma unroll
  for (int i = 0; i < 7; ++i) {
    hsA[i] = (i * h) / 7;
    hlA[i] = ((i + 1) * h + 6) / 7 - hsA[i];
    wsA[i] = (i * w) / 7;
    wlA[i] = ((i + 1) * w + 6) / 7 - wsA[i];
  }
  const float* fp = fmT + c;
  u16* op = pooled + (size_t)n * 25088 + (size_t)c * 49;
  for (int i = 0; i < 7; ++i) {
    int yb = y0 + hsA[i];
    for (int j = 0; j < 7; ++j) {
      int xb = x0 + wsA[j];
      float m = -3.0e38f;
      for (int yy = 0; yy < hlA[i]; ++yy) {
        int y = yb + yy; if (y > 37) y = 37;
        const float* rowp = fp + (size_t)(y * 38) * 512;
        for (int xx = 0; xx < wlA[j]; ++xx) {
          int x = xb + xx; if (x > 37) x = 37;
          m = fmaxf(m, rowp[(size_t)x * 512]);
        }
      }
      op[i * 7 + j] = f2b(m);
    }
  }
}

// ---------- 3. split-K GEMM, E/O 2-deep prefetch; REPS = internal repeat for
// attribution: reps 0..REPS-2 stream SHIFTED k-slices (HBM-like), results kept
// live via asm then discarded; last rep computes the real slice. Output identical.
#define BK 32
template <int NS, int REPS>
__global__ __launch_bounds__(512) void gemm_splitk(
    const u16* __restrict__ A, const float* __restrict__ B,
    float* __restrict__ Cp, int lda, int steps_total) {
  const int N = 4096;
  int nt = blockIdx.x, ks = blockIdx.y;
  int n0 = nt * 64;
  int nsteps = steps_total / NS;  // exact and even

  __shared__ __align__(16) u16 sA[2][256 * 40];  // 40960 B (80B-padded rows)
  __shared__ __align__(16) u16 sB[2][64 * 40];   // 10240 B

  int t = threadIdx.x;
  int lane = t & 63;
  int wid = t >> 6;          // wave owns rows wid*32..+31
  int l4 = lane >> 4, lm = lane & 15;

  int rA = t >> 1, ha = t & 1;          // A staging: row, 16-elem half
  int nB = t & 63, kg = t >> 6;         // B staging: col, 4-k group

  f32x4 acc[2][4];
#pragma unroll
  for (int i = 0; i < 2; ++i)
#pragma unroll
    for (int j = 0; j < 4; ++j) acc[i][j] = (f32x4)(0.f);

  u32x4 ea0, ea1; float eb0, eb1, eb2, eb3;  // set E
  u32x4 oa0, oa1; float ob0, ob1, ob2, ob3;  // set O

  for (int rep = 0; rep < REPS; ++rep) {
    if (rep > 0) {
      // consume acc (keeps prior rep's MFMA chain live vs DCE), then re-zero
#pragma unroll
      for (int i = 0; i < 2; ++i)
#pragma unroll
        for (int j = 0; j < 4; ++j) {
#pragma unroll
          for (int r = 0; r < 4; ++r) {
            float tmp = acc[i][j][r];
            asm volatile("" ::"v"(tmp));
          }
          acc[i][j] = (f32x4)(0.f);
        }
    }
    int eff = (rep == REPS - 1) ? ks : ((ks + rep + 1) % NS);
    int k0 = eff * nsteps * BK;
    const u16* gA = A + (size_t)rA * lda + k0 + ha * 16;
    const float* gB = B + (size_t)(k0 + kg * 4) * N + n0 + nB;

#define LOADG(S, A0, A1, B0, B1, B2, B3)              \
  do {                                                \
    const u16* pa_ = gA + (size_t)(S) * BK;           \
    A0 = *(const u32x4*)(pa_);                        \
    A1 = *(const u32x4*)(pa_ + 8);                    \
    const float* pb_ = gB + (size_t)(S) * BK * N;     \
    B0 = pb_[0];                                      \
    B1 = pb_[(size_t)N];                              \
    B2 = pb_[(size_t)2 * N];                          \
    B3 = pb_[(size_t)3 * N];                          \
  } while (0)

#define STORE(BUF, A0, A1, B0, B1, B2, B3)            \
  do {                                                \
    *(u32x4*)&sA[BUF][rA * 40 + ha * 16] = A0;        \
    *(u32x4*)&sA[BUF][rA * 40 + ha * 16 + 8] = A1;    \
    u32x2 bw_;                                        \
    bw_[0] = (u32)f2b(B0) | ((u32)f2b(B1) << 16);     \
    bw_[1] = (u32)f2b(B2) | ((u32)f2b(B3) << 16);     \
    *(u32x2*)&sB[BUF][nB * 40 + kg * 4] = bw_;        \
  } while (0)

#define COMPUTE(BUF)                                                         \
  do {                                                                       \
    const u16* pa0_ = &sA[BUF][(wid * 32 + lm) * 40 + l4 * 8];               \
    const u16* pb0_ = &sB[BUF][lm * 40 + l4 * 8];                            \
    bf16x8 af0_ = *(const bf16x8*)(pa0_);                                    \
    bf16x8 af1_ = *(const bf16x8*)(pa0_ + 16 * 40);                          \
    bf16x8 bf0_ = *(const bf16x8*)(pb0_);                                    \
    bf16x8 bf1_ = *(const bf16x8*)(pb0_ + 16 * 40);                          \
    bf16x8 bf2_ = *(const bf16x8*)(pb0_ + 32 * 40);                          \
    bf16x8 bf3_ = *(const bf16x8*)(pb0_ + 48 * 40);                          \
    acc[0][0] = __builtin_amdgcn_mfma_f32_16x16x32_bf16(af0_, bf0_, acc[0][0], 0, 0, 0); \
    acc[0][1] = __builtin_amdgcn_mfma_f32_16x16x32_bf16(af0_, bf1_, acc[0][1], 0, 0, 0); \
    acc[0][2] = __builtin_amdgcn_mfma_f32_16x16x32_bf16(af0_, bf2_, acc[0][2], 0, 0, 0); \
    acc[0][3] = __builtin_amdgcn_mfma_f32_16x16x32_bf16(af0_, bf3_, acc[0][3], 0, 0, 0); \
    acc[1][0] = __builtin_amdgcn_mfma_f32_16x16x32_bf16(af1_, bf0_, acc[1][0], 0, 0, 0); \
    acc[1][1] = __builtin_amdgcn_mfma_f32_16x16x32_bf16(af1_, bf1_, acc[1][1], 0, 0, 0); \
    acc[1][2] = __builtin_amdgcn_mfma_f32_16x16x32_bf16(af1_, bf2_, acc[1][2], 0, 0, 0); \
    acc[1][3] = __builtin_amdgcn_mfma_f32_16x16x32_bf16(af1_, bf3_, acc[1][3], 0, 0, 0); \
  } while (0)

    // prologue: L0->E, L1->O, stage E into lds0
    LOADG(0, ea0, ea1, eb0, eb1, eb2, eb3);
    LOADG(1, oa0, oa1, ob0, ob1, ob2, ob3);
    STORE(0, ea0, ea1, eb0, eb1, eb2, eb3);  // waits E only; O stays in flight
    __syncthreads();

    for (int s = 0; s < nsteps; s += 2) {
      if (s + 2 < nsteps) LOADG(s + 2, ea0, ea1, eb0, eb1, eb2, eb3);
      COMPUTE(0);
      STORE(1, oa0, oa1, ob0, ob1, ob2, ob3);  // waits O; E in flight
      __syncthreads();
      if (s + 3 < nsteps) LOADG(s + 3, oa0, oa1, ob0, ob1, ob2, ob3);
      COMPUTE(1);
      if (s + 2 < nsteps) STORE(0, ea0, ea1, eb0, eb1, eb2, eb3);  // waits E; O in flight
      __syncthreads();
    }
#undef LOADG
#undef STORE
#undef COMPUTE
  }

  // epilogue: partial C [ks][256][4096] (last rep's real slice)
#pragma unroll
  for (int m = 0; m < 2; ++m) {
#pragma unroll
    for (int n = 0; n < 4; ++n) {
      int grow = wid * 32 + m * 16 + l4 * 4;
      int gcol = n0 + n * 16 + lm;
      float* cp = Cp + ((size_t)(ks * 256 + grow)) * 4096 + gcol;
#pragma unroll
      for (int r = 0; r < 4; ++r) cp[(size_t)r * 4096] = acc[m][n][r];
    }
  }
}

// ---------- 4. reduce split-K partials + bias + relu -> bf16 (vec4) ----------
__global__ void reduce_bias_relu(const float* __restrict__ Cp,
                                 const float* __restrict__ bias,
                                 u16* __restrict__ outbf, int nsplit) {
  int idx = (blockIdx.x * 256 + threadIdx.x) * 4;  // 256*4096 total elems
  f32x4 s = *(const f32x4*)&bias[idx & 4095];
  for (int k = 0; k < nsplit; ++k) {
    f32x4 v = *(const f32x4*)&Cp[(size_t)k * 1048576 + idx];
#pragma unroll
    for (int j = 0; j < 4; ++j) s[j] += v[j];
  }
  u32x2 o;
  o[0] = (u32)f2b(fmaxf(s[0], 0.f)) | ((u32)f2b(fmaxf(s[1], 0.f)) << 16);
  o[1] = (u32)f2b(fmaxf(s[2], 0.f)) | ((u32)f2b(fmaxf(s[3], 0.f)) << 16);
  *(u32x2*)&outbf[idx] = o;
}

// ---------- 5. heads: locs = fc7@Wloc+bloc ; scores = fc7@Wsc+bsc ----------
__global__ __launch_bounds__(512) void heads_kernel(
    const u16* __restrict__ fc7,
    const float* __restrict__ Wloc, const float* __restrict__ bloc,
    const float* __restrict__ Wsc, const float* __restrict__ bsc,
    float* __restrict__ out) {
  int t = threadIdx.x;
  int c = t & 127, sl = t >> 7;  // 105 active cols, 4 k-slices
  int r0 = blockIdx.x * 4;       // 4 rois per block
  const u16* f0 = fc7 + (size_t)r0 * 4096;
  float acc0 = 0.f, acc1 = 0.f, acc2 = 0.f, acc3 = 0.f;
  if (c < 105) {
    int kb = sl * 1024;
#pragma unroll 4
    for (int k = kb; k < kb + 1024; ++k) {
      float wv = (c < 84) ? Wloc[(size_t)k * 84 + c] : Wsc[(size_t)k * 21 + (c - 84)];
      acc0 += b2f(f0[k]) * wv;
      acc1 += b2f(f0[4096 + k]) * wv;
      acc2 += b2f(f0[8192 + k]) * wv;
      acc3 += b2f(f0[12288 + k]) * wv;
    }
  }
  __shared__ float red[4][4][128];
  red[sl][0][c] = acc0;
  red[sl][1][c] = acc1;
  red[sl][2][c] = acc2;
  red[sl][3][c] = acc3;
  __syncthreads();
  if (sl == 0 && c < 105) {
#pragma unroll
    for (int q = 0; q < 4; ++q) {
      float s = red[0][q][c] + red[1][q][c] + red[2][q][c] + red[3][q][c];
      int r = r0 + q;
      if (c < 84) out[(size_t)r * 84 + c] = s + bloc[c];
      else out[21504 + (size_t)r * 21 + (c - 84)] = s + bsc[c - 84];
    }
  }
}

extern "C" void kernel_launch(void* const* d_in, const int* in_sizes, int n_in,
                              void* d_out, int out_size, void* d_ws, size_t ws_size,
                              hipStream_t stream) {
  const float* fm   = (const float*)d_in[0];
  const float* rois = (const float*)d_in[1];
  const float* W1   = (const float*)d_in[2];
  const float* b1   = (const float*)d_in[3];
  const float* W2   = (const float*)d_in[4];
  const float* b2   = (const float*)d_in[5];
  const float* Wloc = (const float*)d_in[6];
  const float* bloc = (const float*)d_in[7];
  const float* Wsc  = (const float*)d_in[8];
  const float* bsc  = (const float*)d_in[9];
  float* out = (float*)d_out;

  char* ws = (char*)d_ws;
  float* fmT   = (float*)(ws);               // 1444*512*4   = 2,957,312 B
  u16*  pooled = (u16*)(ws + 2957312);       // 256*25088*2  = 12,845,056 B
  u16*  fc6    = (u16*)(ws + 15802368);      // 256*4096*2   = 2,097,152 B
  u16*  fc7    = (u16*)(ws + 17899520);      // 256*4096*2   = 2,097,152 B
  float* Cp    = (float*)(ws + 19996672);    // 14*256*4096*4 = 58,720,256 B (reused)

  transpose_fm<<<dim3(46, 16), dim3(32, 8), 0, stream>>>(fm, fmT);
  roi_pool<<<dim3(256, 2), 256, 0, stream>>>(fmT, rois, pooled);
  // GEMM1: 784 k-steps = 14 splits x 56 steps; REPS=4 for attribution (output identical)
  gemm_splitk<14, 4><<<dim3(64, 14), 512, 0, stream>>>(pooled, W1, Cp, 25088, 784);
  reduce_bias_relu<<<1024, 256, 0, stream>>>(Cp, b1, fc6, 14);
  // GEMM2: 128 k-steps = 8 splits x 16 steps, single pass
  gemm_splitk<8, 1><<<dim3(64, 8), 512, 0, stream>>>(fc6, W2, Cp, 4096, 128);
  reduce_bias_relu<<<1024, 256, 0, stream>>>(Cp, b2, fc7, 8);
  heads_kernel<<<64, 512, 0, stream>>>(fc7, Wloc, bloc, Wsc, bsc, out);
}

// Round 5
// 543.569 us; speedup vs baseline: 1.6701x; 1.6701x over previous
//
#include <hip/hip_runtime.h>
#include <hip/hip_bf16.h>

typedef unsigned int u32;
typedef unsigned short u16;
typedef __attribute__((ext_vector_type(8))) short bf16x8;
typedef __attribute__((ext_vector_type(4))) float f32x4;
typedef __attribute__((ext_vector_type(4))) u32 u32x4;
typedef __attribute__((ext_vector_type(2))) u32 u32x2;

__device__ __forceinline__ u16 f2b(float f) {
  u32 x = __builtin_bit_cast(u32, f);
  x = (x + 0x7FFFu + ((x >> 16) & 1u)) >> 16;  // RNE
  return (u16)x;
}
__device__ __forceinline__ float b2f(u16 h) {
  return __builtin_bit_cast(float, ((u32)h) << 16);
}

// Raw barrier WITHOUT the vmcnt(0) drain __syncthreads forces.
// lgkmcnt(0) retires all LDS reads+writes (the only cross-thread hazard);
// in-flight global loads (private regs) legally stay outstanding across it.
#define BAR()                                              \
  do {                                                     \
    asm volatile("s_waitcnt lgkmcnt(0)" ::: "memory");     \
    __builtin_amdgcn_sched_barrier(0);                     \
    __builtin_amdgcn_s_barrier();                          \
    __builtin_amdgcn_sched_barrier(0);                     \
  } while (0)

// ---------- 1. transpose fm (512, 1444) -> fmT (1444, 512) ----------
__global__ void transpose_fm(const float* __restrict__ fm, float* __restrict__ fmT) {
  __shared__ float tile[32][33];
  int pb = blockIdx.x * 32, cb = blockIdx.y * 32;
  int tx = threadIdx.x, ty = threadIdx.y;  // block (32,8)
#pragma unroll
  for (int i = 0; i < 4; ++i) {
    int c = cb + ty + i * 8;
    int p = pb + tx;
    tile[ty + i * 8][tx] = (p < 1444) ? fm[c * 1444 + p] : 0.f;
  }
  __syncthreads();
#pragma unroll
  for (int i = 0; i < 4; ++i) {
    int p = pb + ty + i * 8;
    int c = cb + tx;
    if (p < 1444) fmT[p * 512 + c] = tile[tx][ty + i * 8];
  }
}

// ---------- 2. RoI adaptive max pool -> pooled bf16 [256][25088] ----------
__global__ void roi_pool(const float* __restrict__ fmT,
                         const float* __restrict__ rois,
                         u16* __restrict__ pooled) {
  int n = blockIdx.x;
  int c = blockIdx.y * 256 + threadIdx.x;  // 0..511
  const float* rp = rois + n * 4;
  int y0 = (int)(rp[0] * 0.0625f);
  int x0 = (int)(rp[1] * 0.0625f);
  int y2 = (int)(rp[2] * 0.0625f);
  int x2 = (int)(rp[3] * 0.0625f);
  int h = y2 - y0 + 1;
  int w = x2 - x0 + 1;
  int hsA[7], hlA[7], wsA[7], wlA[7];
#pragma unroll
  for (int i = 0; i < 7; ++i) {
    hsA[i] = (i * h) / 7;
    hlA[i] = ((i + 1) * h + 6) / 7 - hsA[i];
    wsA[i] = (i * w) / 7;
    wlA[i] = ((i + 1) * w + 6) / 7 - wsA[i];
  }
  const float* fp = fmT + c;
  u16* op = pooled + (size_t)n * 25088 + (size_t)c * 49;
  for (int i = 0; i < 7; ++i) {
    int yb = y0 + hsA[i];
    for (int j = 0; j < 7; ++j) {
      int xb = x0 + wsA[j];
      float m = -3.0e38f;
      for (int yy = 0; yy < hlA[i]; ++yy) {
        int y = yb + yy; if (y > 37) y = 37;
        const float* rowp = fp + (size_t)(y * 38) * 512;
        for (int xx = 0; xx < wlA[j]; ++xx) {
          int x = xb + xx; if (x > 37) x = 37;
          m = fmaxf(m, rowp[(size_t)x * 512]);
        }
      }
      op[i * 7 + j] = f2b(m);
    }
  }
}

// ---------- 3. split-K GEMM, E/O 2-deep reg prefetch + raw-barrier (counted vmcnt) ----------
// Tile 256(full-M) x 64, BK=32, 512 threads = 8 waves, wave = 32 rows x 64 cols.
// The compiler's dependency-counted s_waitcnt waits only the OLDER load set before
// its ds_write; the raw BAR() never drains vmcnt -> the newer set's 6 loads stay
// in flight across the barrier (~1.5 steps of latency hiding).
#define BK 32
template <int NS>
__global__ __launch_bounds__(512) void gemm_splitk(
    const u16* __restrict__ A, const float* __restrict__ B,
    float* __restrict__ Cp, int lda, int steps_total) {
  const int N = 4096;
  int nt = blockIdx.x, ks = blockIdx.y;
  int n0 = nt * 64;
  int nsteps = steps_total / NS;  // exact and even

  __shared__ __align__(16) u16 sA[2][256 * 40];  // 40960 B (80B-padded rows)
  __shared__ __align__(16) u16 sB[2][64 * 40];   // 10240 B

  int t = threadIdx.x;
  int lane = t & 63;
  int wid = t >> 6;          // wave owns rows wid*32..+31
  int l4 = lane >> 4, lm = lane & 15;

  int rA = t >> 1, ha = t & 1;          // A staging: row, 16-elem half
  int nB = t & 63, kg = t >> 6;         // B staging: col, 4-k group

  int k0 = ks * nsteps * BK;
  const u16* gA = A + (size_t)rA * lda + k0 + ha * 16;
  const float* gB = B + (size_t)(k0 + kg * 4) * N + n0 + nB;

  f32x4 acc[2][4];
#pragma unroll
  for (int i = 0; i < 2; ++i)
#pragma unroll
    for (int j = 0; j < 4; ++j) acc[i][j] = (f32x4)(0.f);

  u32x4 ea0, ea1; float eb0, eb1, eb2, eb3;  // set E
  u32x4 oa0, oa1; float ob0, ob1, ob2, ob3;  // set O

#define LOADG(S, A0, A1, B0, B1, B2, B3)              \
  do {                                                \
    const u16* pa_ = gA + (size_t)(S) * BK;           \
    A0 = *(const u32x4*)(pa_);                        \
    A1 = *(const u32x4*)(pa_ + 8);                    \
    const float* pb_ = gB + (size_t)(S) * BK * N;     \
    B0 = pb_[0];                                      \
    B1 = pb_[(size_t)N];                              \
    B2 = pb_[(size_t)2 * N];                          \
    B3 = pb_[(size_t)3 * N];                          \
  } while (0)

#define STORE(BUF, A0, A1, B0, B1, B2, B3)            \
  do {                                                \
    *(u32x4*)&sA[BUF][rA * 40 + ha * 16] = A0;        \
    *(u32x4*)&sA[BUF][rA * 40 + ha * 16 + 8] = A1;    \
    u32x2 bw_;                                        \
    bw_[0] = (u32)f2b(B0) | ((u32)f2b(B1) << 16);     \
    bw_[1] = (u32)f2b(B2) | ((u32)f2b(B3) << 16);     \
    *(u32x2*)&sB[BUF][nB * 40 + kg * 4] = bw_;        \
  } while (0)

#define COMPUTE(BUF)                                                         \
  do {                                                                       \
    const u16* pa0_ = &sA[BUF][(wid * 32 + lm) * 40 + l4 * 8];               \
    const u16* pb0_ = &sB[BUF][lm * 40 + l4 * 8];                            \
    bf16x8 af0_ = *(const bf16x8*)(pa0_);                                    \
    bf16x8 af1_ = *(const bf16x8*)(pa0_ + 16 * 40);                          \
    bf16x8 bf0_ = *(const bf16x8*)(pb0_);                                    \
    bf16x8 bf1_ = *(const bf16x8*)(pb0_ + 16 * 40);                          \
    bf16x8 bf2_ = *(const bf16x8*)(pb0_ + 32 * 40);                          \
    bf16x8 bf3_ = *(const bf16x8*)(pb0_ + 48 * 40);                          \
    acc[0][0] = __builtin_amdgcn_mfma_f32_16x16x32_bf16(af0_, bf0_, acc[0][0], 0, 0, 0); \
    acc[0][1] = __builtin_amdgcn_mfma_f32_16x16x32_bf16(af0_, bf1_, acc[0][1], 0, 0, 0); \
    acc[0][2] = __builtin_amdgcn_mfma_f32_16x16x32_bf16(af0_, bf2_, acc[0][2], 0, 0, 0); \
    acc[0][3] = __builtin_amdgcn_mfma_f32_16x16x32_bf16(af0_, bf3_, acc[0][3], 0, 0, 0); \
    acc[1][0] = __builtin_amdgcn_mfma_f32_16x16x32_bf16(af1_, bf0_, acc[1][0], 0, 0, 0); \
    acc[1][1] = __builtin_amdgcn_mfma_f32_16x16x32_bf16(af1_, bf1_, acc[1][1], 0, 0, 0); \
    acc[1][2] = __builtin_amdgcn_mfma_f32_16x16x32_bf16(af1_, bf2_, acc[1][2], 0, 0, 0); \
    acc[1][3] = __builtin_amdgcn_mfma_f32_16x16x32_bf16(af1_, bf3_, acc[1][3], 0, 0, 0); \
  } while (0)

  // prologue: L0->E, L1->O, stage E into lds0 (waits E only; O stays in flight)
  LOADG(0, ea0, ea1, eb0, eb1, eb2, eb3);
  LOADG(1, oa0, oa1, ob0, ob1, ob2, ob3);
  STORE(0, ea0, ea1, eb0, eb1, eb2, eb3);
  BAR();

  for (int s = 0; s < nsteps; s += 2) {
    if (s + 2 < nsteps) LOADG(s + 2, ea0, ea1, eb0, eb1, eb2, eb3);
    COMPUTE(0);
    STORE(1, oa0, oa1, ob0, ob1, ob2, ob3);  // dep-wait O only; E in flight
    BAR();
    if (s + 3 < nsteps) LOADG(s + 3, oa0, oa1, ob0, ob1, ob2, ob3);
    COMPUTE(1);
    if (s + 2 < nsteps) STORE(0, ea0, ea1, eb0, eb1, eb2, eb3);  // dep-wait E; O in flight
    BAR();
  }

  // epilogue: partial C [ks][256][4096]
#pragma unroll
  for (int m = 0; m < 2; ++m) {
#pragma unroll
    for (int n = 0; n < 4; ++n) {
      int grow = wid * 32 + m * 16 + l4 * 4;
      int gcol = n0 + n * 16 + lm;
      float* cp = Cp + ((size_t)(ks * 256 + grow)) * 4096 + gcol;
#pragma unroll
      for (int r = 0; r < 4; ++r) cp[(size_t)r * 4096] = acc[m][n][r];
    }
  }
#undef LOADG
#undef STORE
#undef COMPUTE
}

// ---------- 4. reduce split-K partials + bias + relu -> bf16 (vec4) ----------
__global__ void reduce_bias_relu(const float* __restrict__ Cp,
                                 const float* __restrict__ bias,
                                 u16* __restrict__ outbf, int nsplit) {
  int idx = (blockIdx.x * 256 + threadIdx.x) * 4;  // 256*4096 total elems
  f32x4 s = *(const f32x4*)&bias[idx & 4095];
  for (int k = 0; k < nsplit; ++k) {
    f32x4 v = *(const f32x4*)&Cp[(size_t)k * 1048576 + idx];
#pragma unroll
    for (int j = 0; j < 4; ++j) s[j] += v[j];
  }
  u32x2 o;
  o[0] = (u32)f2b(fmaxf(s[0], 0.f)) | ((u32)f2b(fmaxf(s[1], 0.f)) << 16);
  o[1] = (u32)f2b(fmaxf(s[2], 0.f)) | ((u32)f2b(fmaxf(s[3], 0.f)) << 16);
  *(u32x2*)&outbf[idx] = o;
}

// ---------- 5. heads: locs = fc7@Wloc+bloc ; scores = fc7@Wsc+bsc ----------
__global__ __launch_bounds__(512) void heads_kernel(
    const u16* __restrict__ fc7,
    const float* __restrict__ Wloc, const float* __restrict__ bloc,
    const float* __restrict__ Wsc, const float* __restrict__ bsc,
    float* __restrict__ out) {
  int t = threadIdx.x;
  int c = t & 127, sl = t >> 7;  // 105 active cols, 4 k-slices
  int r0 = blockIdx.x * 4;       // 4 rois per block
  const u16* f0 = fc7 + (size_t)r0 * 4096;
  float acc0 = 0.f, acc1 = 0.f, acc2 = 0.f, acc3 = 0.f;
  if (c < 105) {
    int kb = sl * 1024;
#pragma unroll 4
    for (int k = kb; k < kb + 1024; ++k) {
      float wv = (c < 84) ? Wloc[(size_t)k * 84 + c] : Wsc[(size_t)k * 21 + (c - 84)];
      acc0 += b2f(f0[k]) * wv;
      acc1 += b2f(f0[4096 + k]) * wv;
      acc2 += b2f(f0[8192 + k]) * wv;
      acc3 += b2f(f0[12288 + k]) * wv;
    }
  }
  __shared__ float red[4][4][128];
  red[sl][0][c] = acc0;
  red[sl][1][c] = acc1;
  red[sl][2][c] = acc2;
  red[sl][3][c] = acc3;
  __syncthreads();
  if (sl == 0 && c < 105) {
#pragma unroll
    for (int q = 0; q < 4; ++q) {
      float s = red[0][q][c] + red[1][q][c] + red[2][q][c] + red[3][q][c];
      int r = r0 + q;
      if (c < 84) out[(size_t)r * 84 + c] = s + bloc[c];
      else out[21504 + (size_t)r * 21 + (c - 84)] = s + bsc[c - 84];
    }
  }
}

extern "C" void kernel_launch(void* const* d_in, const int* in_sizes, int n_in,
                              void* d_out, int out_size, void* d_ws, size_t ws_size,
                              hipStream_t stream) {
  const float* fm   = (const float*)d_in[0];
  const float* rois = (const float*)d_in[1];
  const float* W1   = (const float*)d_in[2];
  const float* b1   = (const float*)d_in[3];
  const float* W2   = (const float*)d_in[4];
  const float* b2   = (const float*)d_in[5];
  const float* Wloc = (const float*)d_in[6];
  const float* bloc = (const float*)d_in[7];
  const float* Wsc  = (const float*)d_in[8];
  const float* bsc  = (const float*)d_in[9];
  float* out = (float*)d_out;

  char* ws = (char*)d_ws;
  float* fmT   = (float*)(ws);               // 1444*512*4   = 2,957,312 B
  u16*  pooled = (u16*)(ws + 2957312);       // 256*25088*2  = 12,845,056 B
  u16*  fc6    = (u16*)(ws + 15802368);      // 256*4096*2   = 2,097,152 B
  u16*  fc7    = (u16*)(ws + 17899520);      // 256*4096*2   = 2,097,152 B
  float* Cp    = (float*)(ws + 19996672);    // 14*256*4096*4 = 58,720,256 B (reused)

  transpose_fm<<<dim3(46, 16), dim3(32, 8), 0, stream>>>(fm, fmT);
  roi_pool<<<dim3(256, 2), 256, 0, stream>>>(fmT, rois, pooled);
  // GEMM1: 784 k-steps = 14 splits x 56 steps (even)
  gemm_splitk<14><<<dim3(64, 14), 512, 0, stream>>>(pooled, W1, Cp, 25088, 784);
  reduce_bias_relu<<<1024, 256, 0, stream>>>(Cp, b1, fc6, 14);
  // GEMM2: 128 k-steps = 8 splits x 16 steps (even)
  gemm_splitk<8><<<dim3(64, 8), 512, 0, stream>>>(fc6, W2, Cp, 4096, 128);
  reduce_bias_relu<<<1024, 256, 0, stream>>>(Cp, b2, fc7, 8);
  heads_kernel<<<64, 512, 0, stream>>>(fc7, Wloc, bloc, Wsc, bsc, out);
}

// Round 6
// 529.238 us; speedup vs baseline: 1.7154x; 1.0271x over previous
//
#include <hip/hip_runtime.h>
#include <hip/hip_bf16.h>

typedef unsigned int u32;
typedef unsigned short u16;
typedef __attribute__((ext_vector_type(8))) short bf16x8;
typedef __attribute__((ext_vector_type(4))) float f32x4;
typedef __attribute__((ext_vector_type(2))) u32 u32x2;

__device__ __forceinline__ u16 f2b(float f) {
  u32 x = __builtin_bit_cast(u32, f);
  x = (x + 0x7FFFu + ((x >> 16) & 1u)) >> 16;  // RNE
  return (u16)x;
}
__device__ __forceinline__ float b2f(u16 h) {
  return __builtin_bit_cast(float, ((u32)h) << 16);
}

// global -> LDS direct DMA, 16B per lane (no destination registers).
__device__ __forceinline__ void gld_lds16(const u16* g, u16* l) {
  __builtin_amdgcn_global_load_lds(
      (const __attribute__((address_space(1))) u32*)g,
      (__attribute__((address_space(3))) u32*)l, 16, 0, 0);
}

// ---------- 1. transpose fm (512, 1444) -> fmT (1444, 512) ----------
__global__ void transpose_fm(const float* __restrict__ fm, float* __restrict__ fmT) {
  __shared__ float tile[32][33];
  int pb = blockIdx.x * 32, cb = blockIdx.y * 32;
  int tx = threadIdx.x, ty = threadIdx.y;  // block (32,8)
#pragma unroll
  for (int i = 0; i < 4; ++i) {
    int c = cb + ty + i * 8;
    int p = pb + tx;
    tile[ty + i * 8][tx] = (p < 1444) ? fm[c * 1444 + p] : 0.f;
  }
  __syncthreads();
#pragma unroll
  for (int i = 0; i < 4; ++i) {
    int p = pb + ty + i * 8;
    int c = cb + tx;
    if (p < 1444) fmT[p * 512 + c] = tile[tx][ty + i * 8];
  }
}

// ---------- 2. RoI adaptive max pool -> pooled bf16 [256][25088] ----------
__global__ void roi_pool(const float* __restrict__ fmT,
                         const float* __restrict__ rois,
                         u16* __restrict__ pooled) {
  int n = blockIdx.x;
  int c = blockIdx.y * 256 + threadIdx.x;  // 0..511
  const float* rp = rois + n * 4;
  int y0 = (int)(rp[0] * 0.0625f);
  int x0 = (int)(rp[1] * 0.0625f);
  int y2 = (int)(rp[2] * 0.0625f);
  int x2 = (int)(rp[3] * 0.0625f);
  int h = y2 - y0 + 1;
  int w = x2 - x0 + 1;
  int hsA[7], hlA[7], wsA[7], wlA[7];
#pragma unroll
  for (int i = 0; i < 7; ++i) {
    hsA[i] = (i * h) / 7;
    hlA[i] = ((i + 1) * h + 6) / 7 - hsA[i];
    wsA[i] = (i * w) / 7;
    wlA[i] = ((i + 1) * w + 6) / 7 - wsA[i];
  }
  const float* fp = fmT + c;
  u16* op = pooled + (size_t)n * 25088 + (size_t)c * 49;
  for (int i = 0; i < 7; ++i) {
    int yb = y0 + hsA[i];
    for (int j = 0; j < 7; ++j) {
      int xb = x0 + wsA[j];
      float m = -3.0e38f;
      for (int yy = 0; yy < hlA[i]; ++yy) {
        int y = yb + yy; if (y > 37) y = 37;
        const float* rowp = fp + (size_t)(y * 38) * 512;
        for (int xx = 0; xx < wlA[j]; ++xx) {
          int x = xb + xx; if (x > 37) x = 37;
          m = fmaxf(m, rowp[(size_t)x * 512]);
        }
      }
      op[i * 7 + j] = f2b(m);
    }
  }
}

// ---------- 3. split-K GEMM: A via global_load_lds (pre-swizzled source),
// B via E/O 2-deep register prefetch; raw barrier + hand-counted vmcnt(4)
// so B's 4 newer loads stay in flight across every barrier.
// Tile 256(full-M) x 64, BK=32, 512 threads = 8 waves, wave = 32 rows x 64 cols.
#define BK 32
template <int NS>
__global__ __launch_bounds__(512) void gemm_splitk(
    const u16* __restrict__ A, const float* __restrict__ B,
    float* __restrict__ Cp, int lda, int steps_total) {
  const int N = 4096;
  int nt = blockIdx.x, ks = blockIdx.y;
  int n0 = nt * 64;
  int nsteps = steps_total / NS;  // exact, even, >= 4
  int k0 = ks * nsteps * BK;

  // sA: linear [256][32] bf16 (glld dest must be linear); conflict-freedom via
  // source-side chunk swizzle cg = cs ^ ((row>>1)&3), same xor on read side.
  __shared__ __align__(16) u16 sA[2][256 * 32];  // 32768 B
  __shared__ __align__(16) u16 sB[2][64 * 40];   // 10240 B (80B-padded rows)

  int t = threadIdx.x;
  int lane = t & 63;
  int wid = t >> 6;          // wave owns rows wid*32..+31
  int l4 = lane >> 4, lm = lane & 15;

  // --- A glld source: issue i covers rows wid*32+i*16 .. +16, lane l -> row +l/4,
  // chunk slot l&3 holds global chunk (l&3)^((row>>1)&3) = (l&3)^((l>>3)&3).
  int acg = (lane & 3) ^ ((lane >> 3) & 3);
  const u16* gA0 = A + (size_t)(wid * 32 + (lane >> 2)) * lda + k0 + acg * 8;
  const u16* gA1 = gA0 + (size_t)16 * lda;
  int ldsAoff0 = wid * 1024;        // u16 elems: (wid*32 rows)*32
  int ldsAoff1 = wid * 1024 + 512;  // +16 rows

  // --- B staging: 4 strided scalar f32 loads -> pack bf16 -> 1 ds_write_b64
  int nB = t & 63, kg = t >> 6;
  const float* gB = B + (size_t)(k0 + kg * 4) * N + n0 + nB;

  f32x4 acc[2][4];
#pragma unroll
  for (int i = 0; i < 2; ++i)
#pragma unroll
    for (int j = 0; j < 4; ++j) acc[i][j] = (f32x4)(0.f);

  float eb0, eb1, eb2, eb3;  // set E
  float ob0, ob1, ob2, ob3;  // set O

#define GLLD(S, BUF)                                      \
  do {                                                    \
    const u16* base_ = gA0 + (size_t)(S) * BK;            \
    gld_lds16(base_, &sA[BUF][ldsAoff0]);                 \
    gld_lds16(gA1 + (size_t)(S) * BK, &sA[BUF][ldsAoff1]);\
    (void)base_;                                          \
    __builtin_amdgcn_sched_barrier(0);                    \
  } while (0)

#define LOADB(S, B0, B1, B2, B3)                      \
  do {                                                \
    const float* pb_ = gB + (size_t)(S) * BK * N;     \
    B0 = pb_[0];                                      \
    B1 = pb_[(size_t)N];                              \
    B2 = pb_[(size_t)2 * N];                          \
    B3 = pb_[(size_t)3 * N];                          \
  } while (0)

#define STOREB(BUF, B0, B1, B2, B3)                   \
  do {                                                \
    u32x2 bw_;                                        \
    bw_[0] = (u32)f2b(B0) | ((u32)f2b(B1) << 16);     \
    bw_[1] = (u32)f2b(B2) | ((u32)f2b(B3) << 16);     \
    *(u32x2*)&sB[BUF][nB * 40 + kg * 4] = bw_;        \
  } while (0)

#define COMPUTE(BUF)                                                         \
  do {                                                                       \
    int sig_ = (lm >> 1) & 3;                                                \
    const u16* pa0_ = &sA[BUF][(wid * 32 + lm) * 32 + ((l4 ^ sig_) * 8)];    \
    const u16* pb0_ = &sB[BUF][lm * 40 + l4 * 8];                            \
    bf16x8 af0_ = *(const bf16x8*)(pa0_);                                    \
    bf16x8 af1_ = *(const bf16x8*)(pa0_ + 16 * 32);                          \
    bf16x8 bf0_ = *(const bf16x8*)(pb0_);                                    \
    bf16x8 bf1_ = *(const bf16x8*)(pb0_ + 16 * 40);                          \
    bf16x8 bf2_ = *(const bf16x8*)(pb0_ + 32 * 40);                          \
    bf16x8 bf3_ = *(const bf16x8*)(pb0_ + 48 * 40);                          \
    acc[0][0] = __builtin_amdgcn_mfma_f32_16x16x32_bf16(af0_, bf0_, acc[0][0], 0, 0, 0); \
    acc[0][1] = __builtin_amdgcn_mfma_f32_16x16x32_bf16(af0_, bf1_, acc[0][1], 0, 0, 0); \
    acc[0][2] = __builtin_amdgcn_mfma_f32_16x16x32_bf16(af0_, bf2_, acc[0][2], 0, 0, 0); \
    acc[0][3] = __builtin_amdgcn_mfma_f32_16x16x32_bf16(af0_, bf3_, acc[0][3], 0, 0, 0); \
    acc[1][0] = __builtin_amdgcn_mfma_f32_16x16x32_bf16(af1_, bf0_, acc[1][0], 0, 0, 0); \
    acc[1][1] = __builtin_amdgcn_mfma_f32_16x16x32_bf16(af1_, bf1_, acc[1][1], 0, 0, 0); \
    acc[1][2] = __builtin_amdgcn_mfma_f32_16x16x32_bf16(af1_, bf2_, acc[1][2], 0, 0, 0); \
    acc[1][3] = __builtin_amdgcn_mfma_f32_16x16x32_bf16(af1_, bf3_, acc[1][3], 0, 0, 0); \
  } while (0)

  // barrier with counted vmcnt: the 2 glld (oldest) must retire, the 4 newest
  // B loads stay in flight (vmcnt retires strictly in issue order).
#define BARV(NVM)                                                   \
  do {                                                              \
    asm volatile("s_waitcnt vmcnt(" #NVM ") lgkmcnt(0)" ::: "memory"); \
    __builtin_amdgcn_sched_barrier(0);                              \
    __builtin_amdgcn_s_barrier();                                   \
    __builtin_amdgcn_sched_barrier(0);                              \
  } while (0)

  // prologue: glld tile0 -> buf0 (issued FIRST), then B(0),B(1) to regs;
  // STOREB(0)'s dependency wait on B(0) also retires the older gllds.
  GLLD(0, 0);
  LOADB(0, eb0, eb1, eb2, eb3);
  LOADB(1, ob0, ob1, ob2, ob3);
  STOREB(0, eb0, eb1, eb2, eb3);
  asm volatile("s_waitcnt lgkmcnt(0)" ::: "memory");
  __builtin_amdgcn_sched_barrier(0);
  __builtin_amdgcn_s_barrier();
  __builtin_amdgcn_sched_barrier(0);

  // invariant at loop top: buf0 = tile s staged; O = B(s+1); E free.
  for (int s = 0; s + 3 < nsteps; s += 2) {
    GLLD(s + 1, 1);                      // A(s+1) -> buf1 (DMA, no regs)
    LOADB(s + 2, eb0, eb1, eb2, eb3);    // B(s+2) -> E (stays in flight)
    COMPUTE(0);                          // tile s
    STOREB(1, ob0, ob1, ob2, ob3);       // B(s+1) -> buf1 (dep-waits O only)
    BARV(4);                             // glld retired; E's 4 loads survive

    GLLD(s + 2, 0);                      // A(s+2) -> buf0
    LOADB(s + 3, ob0, ob1, ob2, ob3);    // B(s+3) -> O
    COMPUTE(1);                          // tile s+1
    STOREB(0, eb0, eb1, eb2, eb3);       // B(s+2) -> buf0
    BARV(4);
  }
  // tail: steps nsteps-2 (in buf0), nsteps-1; O = B(nsteps-1)
  GLLD(nsteps - 1, 1);
  COMPUTE(0);
  STOREB(1, ob0, ob1, ob2, ob3);
  BARV(0);
  COMPUTE(1);

  // epilogue: partial C [ks][256][4096]
#pragma unroll
  for (int m = 0; m < 2; ++m) {
#pragma unroll
    for (int n = 0; n < 4; ++n) {
      int grow = wid * 32 + m * 16 + l4 * 4;
      int gcol = n0 + n * 16 + lm;
      float* cp = Cp + ((size_t)(ks * 256 + grow)) * 4096 + gcol;
#pragma unroll
      for (int r = 0; r < 4; ++r) cp[(size_t)r * 4096] = acc[m][n][r];
    }
  }
#undef GLLD
#undef LOADB
#undef STOREB
#undef COMPUTE
#undef BARV
}

// ---------- 4. reduce split-K partials + bias + relu -> bf16 (vec4) ----------
__global__ void reduce_bias_relu(const float* __restrict__ Cp,
                                 const float* __restrict__ bias,
                                 u16* __restrict__ outbf, int nsplit) {
  int idx = (blockIdx.x * 256 + threadIdx.x) * 4;  // 256*4096 total elems
  f32x4 s = *(const f32x4*)&bias[idx & 4095];
  for (int k = 0; k < nsplit; ++k) {
    f32x4 v = *(const f32x4*)&Cp[(size_t)k * 1048576 + idx];
#pragma unroll
    for (int j = 0; j < 4; ++j) s[j] += v[j];
  }
  u32x2 o;
  o[0] = (u32)f2b(fmaxf(s[0], 0.f)) | ((u32)f2b(fmaxf(s[1], 0.f)) << 16);
  o[1] = (u32)f2b(fmaxf(s[2], 0.f)) | ((u32)f2b(fmaxf(s[3], 0.f)) << 16);
  *(u32x2*)&outbf[idx] = o;
}

// ---------- 5. heads: locs = fc7@Wloc+bloc ; scores = fc7@Wsc+bsc ----------
__global__ __launch_bounds__(512) void heads_kernel(
    const u16* __restrict__ fc7,
    const float* __restrict__ Wloc, const float* __restrict__ bloc,
    const float* __restrict__ Wsc, const float* __restrict__ bsc,
    float* __restrict__ out) {
  int t = threadIdx.x;
  int c = t & 127, sl = t >> 7;  // 105 active cols, 4 k-slices
  int r0 = blockIdx.x * 4;       // 4 rois per block
  const u16* f0 = fc7 + (size_t)r0 * 4096;
  float acc0 = 0.f, acc1 = 0.f, acc2 = 0.f, acc3 = 0.f;
  if (c < 105) {
    int kb = sl * 1024;
#pragma unroll 4
    for (int k = kb; k < kb + 1024; ++k) {
      float wv = (c < 84) ? Wloc[(size_t)k * 84 + c] : Wsc[(size_t)k * 21 + (c - 84)];
      acc0 += b2f(f0[k]) * wv;
      acc1 += b2f(f0[4096 + k]) * wv;
      acc2 += b2f(f0[8192 + k]) * wv;
      acc3 += b2f(f0[12288 + k]) * wv;
    }
  }
  __shared__ float red[4][4][128];
  red[sl][0][c] = acc0;
  red[sl][1][c] = acc1;
  red[sl][2][c] = acc2;
  red[sl][3][c] = acc3;
  __syncthreads();
  if (sl == 0 && c < 105) {
#pragma unroll
    for (int q = 0; q < 4; ++q) {
      float s = red[0][q][c] + red[1][q][c] + red[2][q][c] + red[3][q][c];
      int r = r0 + q;
      if (c < 84) out[(size_t)r * 84 + c] = s + bloc[c];
      else out[21504 + (size_t)r * 21 + (c - 84)] = s + bsc[c - 84];
    }
  }
}

extern "C" void kernel_launch(void* const* d_in, const int* in_sizes, int n_in,
                              void* d_out, int out_size, void* d_ws, size_t ws_size,
                              hipStream_t stream) {
  const float* fm   = (const float*)d_in[0];
  const float* rois = (const float*)d_in[1];
  const float* W1   = (const float*)d_in[2];
  const float* b1   = (const float*)d_in[3];
  const float* W2   = (const float*)d_in[4];
  const float* b2   = (const float*)d_in[5];
  const float* Wloc = (const float*)d_in[6];
  const float* bloc = (const float*)d_in[7];
  const float* Wsc  = (const float*)d_in[8];
  const float* bsc  = (const float*)d_in[9];
  float* out = (float*)d_out;

  char* ws = (char*)d_ws;
  float* fmT   = (float*)(ws);               // 1444*512*4   = 2,957,312 B
  u16*  pooled = (u16*)(ws + 2957312);       // 256*25088*2  = 12,845,056 B
  u16*  fc6    = (u16*)(ws + 15802368);      // 256*4096*2   = 2,097,152 B
  u16*  fc7    = (u16*)(ws + 17899520);      // 256*4096*2   = 2,097,152 B
  float* Cp    = (float*)(ws + 19996672);    // 14*256*4096*4 = 58,720,256 B (reused)

  transpose_fm<<<dim3(46, 16), dim3(32, 8), 0, stream>>>(fm, fmT);
  roi_pool<<<dim3(256, 2), 256, 0, stream>>>(fmT, rois, pooled);
  // GEMM1: 784 k-steps = 14 splits x 56 steps (even)
  gemm_splitk<14><<<dim3(64, 14), 512, 0, stream>>>(pooled, W1, Cp, 25088, 784);
  reduce_bias_relu<<<1024, 256, 0, stream>>>(Cp, b1, fc6, 14);
  // GEMM2: 128 k-steps = 8 splits x 16 steps (even)
  gemm_splitk<8><<<dim3(64, 8), 512, 0, stream>>>(fc6, W2, Cp, 4096, 128);
  reduce_bias_relu<<<1024, 256, 0, stream>>>(Cp, b2, fc7, 8);
  heads_kernel<<<64, 512, 0, stream>>>(fc7, Wloc, bloc, Wsc, bsc, out);
}

// Round 7
// 411.318 us; speedup vs baseline: 2.2071x; 1.2867x over previous
//
#include <hip/hip_runtime.h>
#include <hip/hip_bf16.h>

typedef unsigned int u32;
typedef unsigned short u16;
typedef __attribute__((ext_vector_type(8))) short bf16x8;
typedef __attribute__((ext_vector_type(4))) float f32x4;
typedef __attribute__((ext_vector_type(4))) u32 u32x4;
typedef __attribute__((ext_vector_type(2))) u32 u32x2;

__device__ __forceinline__ u16 f2b(float f) {
  u32 x = __builtin_bit_cast(u32, f);
  x = (x + 0x7FFFu + ((x >> 16) & 1u)) >> 16;  // RNE
  return (u16)x;
}
__device__ __forceinline__ float b2f(u16 h) {
  return __builtin_bit_cast(float, ((u32)h) << 16);
}

// global -> LDS direct DMA, 16B per lane (no destination registers).
__device__ __forceinline__ void gld_lds16(const u16* g, u16* l) {
  __builtin_amdgcn_global_load_lds(
      (const __attribute__((address_space(1))) u32*)g,
      (__attribute__((address_space(3))) u32*)l, 16, 0, 0);
}

// ---------- 1. transpose fm (512, 1444) -> fmT (1444, 512) ----------
__global__ void transpose_fm(const float* __restrict__ fm, float* __restrict__ fmT) {
  __shared__ float tile[32][33];
  int pb = blockIdx.x * 32, cb = blockIdx.y * 32;
  int tx = threadIdx.x, ty = threadIdx.y;  // block (32,8)
#pragma unroll
  for (int i = 0; i < 4; ++i) {
    int c = cb + ty + i * 8;
    int p = pb + tx;
    tile[ty + i * 8][tx] = (p < 1444) ? fm[c * 1444 + p] : 0.f;
  }
  __syncthreads();
#pragma unroll
  for (int i = 0; i < 4; ++i) {
    int p = pb + ty + i * 8;
    int c = cb + tx;
    if (p < 1444) fmT[p * 512 + c] = tile[tx][ty + i * 8];
  }
}

// ---------- 2. RoI adaptive max pool -> pooled bf16 [256][25088] ----------
__global__ void roi_pool(const float* __restrict__ fmT,
                         const float* __restrict__ rois,
                         u16* __restrict__ pooled) {
  int n = blockIdx.x;
  int c = blockIdx.y * 256 + threadIdx.x;  // 0..511
  const float* rp = rois + n * 4;
  int y0 = (int)(rp[0] * 0.0625f);
  int x0 = (int)(rp[1] * 0.0625f);
  int y2 = (int)(rp[2] * 0.0625f);
  int x2 = (int)(rp[3] * 0.0625f);
  int h = y2 - y0 + 1;
  int w = x2 - x0 + 1;
  int hsA[7], hlA[7], wsA[7], wlA[7];
#pragma unroll
  for (int i = 0; i < 7; ++i) {
    hsA[i] = (i * h) / 7;
    hlA[i] = ((i + 1) * h + 6) / 7 - hsA[i];
    wsA[i] = (i * w) / 7;
    wlA[i] = ((i + 1) * w + 6) / 7 - wsA[i];
  }
  const float* fp = fmT + c;
  u16* op = pooled + (size_t)n * 25088 + (size_t)c * 49;
  for (int i = 0; i < 7; ++i) {
    int yb = y0 + hsA[i];
    for (int j = 0; j < 7; ++j) {
      int xb = x0 + wsA[j];
      float m = -3.0e38f;
      for (int yy = 0; yy < hlA[i]; ++yy) {
        int y = yb + yy; if (y > 37) y = 37;
        const float* rowp = fp + (size_t)(y * 38) * 512;
        for (int xx = 0; xx < wlA[j]; ++xx) {
          int x = xb + xx; if (x > 37) x = 37;
          m = fmaxf(m, rowp[(size_t)x * 512]);
        }
      }
      op[i * 7 + j] = f2b(m);
    }
  }
}

// ---------- 3. split-K GEMM, tile 256(full-M) x 128, BK=32 ----------
// A via global_load_lds (source-swizzled, linear LDS dest); B via E/O 2-deep
// register prefetch; raw barrier with hand-counted vmcnt(8) so B's 8 newest
// loads stay in flight across every barrier.
// BN=128 halves the L3 re-read of A vs BN=64 (822 MB -> 411 MB per pass).
// 512 threads = 8 waves (4x2 of 64x64). VGPR capped for 2 blocks/CU.
#define BK 32
template <int NS>
__global__ __launch_bounds__(512, 4) void gemm_splitk(
    const u16* __restrict__ A, const float* __restrict__ B,
    float* __restrict__ Cp, int lda, int steps_total) {
  const int N = 4096;
  int nt = blockIdx.x, ks = blockIdx.y;
  int n0 = nt * 128;
  int nsteps = steps_total / NS;  // exact, even, >= 4
  int k0 = ks * nsteps * BK;

  // sA: linear [256][32] bf16 (glld dest must be linear); conflict-freedom via
  // source-side chunk swizzle cg = cs ^ ((row>>1)&3), same xor on read side.
  __shared__ __align__(16) u16 sA[2][256 * 32];  // 32768 B
  __shared__ __align__(16) u16 sB[2][128 * 40];  // 20480 B (80B-padded rows)

  int t = threadIdx.x;
  int lane = t & 63;
  int wid = t >> 6;
  int wm = wid >> 1, wn = wid & 1;  // wave = 64x64 at (wm*64, wn*64)
  int l4 = lane >> 4, lm = lane & 15;

  // --- A glld: issue i covers rows wid*32+i*16..+16; lane l -> row +l/4,
  // slot l&3 holds global chunk (l&3)^((row>>1)&3) = (l&3)^((l>>3)&3).
  int acg = (lane & 3) ^ ((lane >> 3) & 3);
  const u16* gA0 = A + (size_t)(wid * 32 + (lane >> 2)) * lda + k0 + acg * 8;
  const u16* gA1 = gA0 + (size_t)16 * lda;
  int ldsAoff0 = wid * 1024;        // u16 elems
  int ldsAoff1 = wid * 1024 + 512;

  // --- B staging: 8 strided f32 loads -> pack bf16 -> 1 ds_write_b128
  int nB = t & 127, kg = t >> 7;  // col, 8-k group (kg 0..3)
  const float* gB = B + (size_t)(k0 + kg * 8) * N + n0 + nB;

  f32x4 acc[4][4];
#pragma unroll
  for (int i = 0; i < 4; ++i)
#pragma unroll
    for (int j = 0; j < 4; ++j) acc[i][j] = (f32x4)(0.f);

  float eb[8], ob[8];  // E/O register sets for B

#define GLLD(S, BUF)                                       \
  do {                                                     \
    gld_lds16(gA0 + (size_t)(S) * BK, &sA[BUF][ldsAoff0]); \
    gld_lds16(gA1 + (size_t)(S) * BK, &sA[BUF][ldsAoff1]); \
    __builtin_amdgcn_sched_barrier(0);                     \
  } while (0)

#define LOADB(S, RB)                                  \
  do {                                                \
    const float* pb_ = gB + (size_t)(S) * BK * N;     \
    _Pragma("unroll")                                 \
    for (int i_ = 0; i_ < 8; ++i_) RB[i_] = pb_[(size_t)i_ * N]; \
  } while (0)

#define STOREB(BUF, RB)                                             \
  do {                                                              \
    u32x4 bw_;                                                      \
    bw_[0] = (u32)f2b(RB[0]) | ((u32)f2b(RB[1]) << 16);             \
    bw_[1] = (u32)f2b(RB[2]) | ((u32)f2b(RB[3]) << 16);             \
    bw_[2] = (u32)f2b(RB[4]) | ((u32)f2b(RB[5]) << 16);             \
    bw_[3] = (u32)f2b(RB[6]) | ((u32)f2b(RB[7]) << 16);             \
    *(u32x4*)&sB[BUF][nB * 40 + kg * 8] = bw_;                      \
  } while (0)

#define COMPUTE(BUF)                                                         \
  do {                                                                       \
    int sig_ = (lm >> 1) & 3;                                                \
    const u16* pa0_ = &sA[BUF][(wm * 64 + lm) * 32 + ((l4 ^ sig_) * 8)];     \
    const u16* pb0_ = &sB[BUF][(wn * 64 + lm) * 40 + l4 * 8];                \
    bf16x8 af_[4], bf_[4];                                                   \
    _Pragma("unroll")                                                        \
    for (int m_ = 0; m_ < 4; ++m_) af_[m_] = *(const bf16x8*)(pa0_ + m_ * 16 * 32); \
    _Pragma("unroll")                                                        \
    for (int n_ = 0; n_ < 4; ++n_) bf_[n_] = *(const bf16x8*)(pb0_ + n_ * 16 * 40); \
    _Pragma("unroll")                                                        \
    for (int m_ = 0; m_ < 4; ++m_)                                           \
      _Pragma("unroll")                                                      \
      for (int n_ = 0; n_ < 4; ++n_)                                         \
        acc[m_][n_] = __builtin_amdgcn_mfma_f32_16x16x32_bf16(af_[m_], bf_[n_], acc[m_][n_], 0, 0, 0); \
  } while (0)

  // barrier with counted vmcnt: the 2 glld (older) must retire; the 8 newest
  // B loads stay in flight (vmcnt retires strictly in issue order).
#define BARV(NVM)                                                      \
  do {                                                                 \
    asm volatile("s_waitcnt vmcnt(" #NVM ") lgkmcnt(0)" ::: "memory"); \
    __builtin_amdgcn_sched_barrier(0);                                 \
    __builtin_amdgcn_s_barrier();                                      \
    __builtin_amdgcn_sched_barrier(0);                                 \
  } while (0)

  // prologue
  GLLD(0, 0);
  LOADB(0, eb);
  LOADB(1, ob);
  STOREB(0, eb);  // dep-wait retires glld(0)+E; O stays in flight
  asm volatile("s_waitcnt lgkmcnt(0)" ::: "memory");
  __builtin_amdgcn_sched_barrier(0);
  __builtin_amdgcn_s_barrier();
  __builtin_amdgcn_sched_barrier(0);

  // invariant at loop top: buf0 = tile s staged; O = B(s+1); E free.
  for (int s = 0; s + 3 < nsteps; s += 2) {
    GLLD(s + 1, 1);
    LOADB(s + 2, eb);
    COMPUTE(0);
    STOREB(1, ob);   // dep-waits O only; E's 8 loads in flight
    BARV(8);         // glld retired; E survives the barrier

    GLLD(s + 2, 0);
    LOADB(s + 3, ob);
    COMPUTE(1);
    STOREB(0, eb);
    BARV(8);
  }
  // tail: tiles nsteps-2 (buf0), nsteps-1; O = B(nsteps-1)
  GLLD(nsteps - 1, 1);
  COMPUTE(0);
  STOREB(1, ob);
  BARV(0);
  COMPUTE(1);

  // epilogue: partial C [ks][256][4096]
#pragma unroll
  for (int m = 0; m < 4; ++m) {
#pragma unroll
    for (int n = 0; n < 4; ++n) {
      int grow = wm * 64 + m * 16 + l4 * 4;
      int gcol = n0 + wn * 64 + n * 16 + lm;
      float* cp = Cp + ((size_t)(ks * 256 + grow)) * 4096 + gcol;
#pragma unroll
      for (int r = 0; r < 4; ++r) cp[(size_t)r * 4096] = acc[m][n][r];
    }
  }
#undef GLLD
#undef LOADB
#undef STOREB
#undef COMPUTE
#undef BARV
}

// ---------- 4. reduce split-K partials + bias + relu -> bf16 (vec4) ----------
__global__ void reduce_bias_relu(const float* __restrict__ Cp,
                                 const float* __restrict__ bias,
                                 u16* __restrict__ outbf, int nsplit) {
  int idx = (blockIdx.x * 256 + threadIdx.x) * 4;  // 256*4096 total elems
  f32x4 s = *(const f32x4*)&bias[idx & 4095];
  for (int k = 0; k < nsplit; ++k) {
    f32x4 v = *(const f32x4*)&Cp[(size_t)k * 1048576 + idx];
#pragma unroll
    for (int j = 0; j < 4; ++j) s[j] += v[j];
  }
  u32x2 o;
  o[0] = (u32)f2b(fmaxf(s[0], 0.f)) | ((u32)f2b(fmaxf(s[1], 0.f)) << 16);
  o[1] = (u32)f2b(fmaxf(s[2], 0.f)) | ((u32)f2b(fmaxf(s[3], 0.f)) << 16);
  *(u32x2*)&outbf[idx] = o;
}

// ---------- 5. heads: one roi per block (256 blocks) ----------
__global__ __launch_bounds__(512) void heads_kernel(
    const u16* __restrict__ fc7,
    const float* __restrict__ Wloc, const float* __restrict__ bloc,
    const float* __restrict__ Wsc, const float* __restrict__ bsc,
    float* __restrict__ out) {
  int t = threadIdx.x;
  int c = t & 127, sl = t >> 7;  // 105 active cols, 4 k-slices
  int r = blockIdx.x;
  const u16* f0 = fc7 + (size_t)r * 4096;
  float acc = 0.f;
  if (c < 105) {
    int kb = sl * 1024;
#pragma unroll 4
    for (int k = kb; k < kb + 1024; ++k) {
      float wv = (c < 84) ? Wloc[(size_t)k * 84 + c] : Wsc[(size_t)k * 21 + (c - 84)];
      acc += b2f(f0[k]) * wv;
    }
  }
  __shared__ float red[4][128];
  red[sl][c] = acc;
  __syncthreads();
  if (sl == 0 && c < 105) {
    float s = red[0][c] + red[1][c] + red[2][c] + red[3][c];
    if (c < 84) out[(size_t)r * 84 + c] = s + bloc[c];
    else out[21504 + (size_t)r * 21 + (c - 84)] = s + bsc[c - 84];
  }
}

extern "C" void kernel_launch(void* const* d_in, const int* in_sizes, int n_in,
                              void* d_out, int out_size, void* d_ws, size_t ws_size,
                              hipStream_t stream) {
  const float* fm   = (const float*)d_in[0];
  const float* rois = (const float*)d_in[1];
  const float* W1   = (const float*)d_in[2];
  const float* b1   = (const float*)d_in[3];
  const float* W2   = (const float*)d_in[4];
  const float* b2   = (const float*)d_in[5];
  const float* Wloc = (const float*)d_in[6];
  const float* bloc = (const float*)d_in[7];
  const float* Wsc  = (const float*)d_in[8];
  const float* bsc  = (const float*)d_in[9];
  float* out = (float*)d_out;

  char* ws = (char*)d_ws;
  float* fmT   = (float*)(ws);               // 1444*512*4   = 2,957,312 B
  u16*  pooled = (u16*)(ws + 2957312);       // 256*25088*2  = 12,845,056 B
  u16*  fc6    = (u16*)(ws + 15802368);      // 256*4096*2   = 2,097,152 B
  u16*  fc7    = (u16*)(ws + 17899520);      // 256*4096*2   = 2,097,152 B
  float* Cp    = (float*)(ws + 19996672);    // 14*256*4096*4 = 58,720,256 B (reused)

  transpose_fm<<<dim3(46, 16), dim3(32, 8), 0, stream>>>(fm, fmT);
  roi_pool<<<dim3(256, 2), 256, 0, stream>>>(fmT, rois, pooled);
  // GEMM1: 784 k-steps = 14 splits x 56 steps (even); 32 n-tiles of 128
  gemm_splitk<14><<<dim3(32, 14), 512, 0, stream>>>(pooled, W1, Cp, 25088, 784);
  reduce_bias_relu<<<1024, 256, 0, stream>>>(Cp, b1, fc6, 14);
  // GEMM2: 128 k-steps = 8 splits x 16 steps (even)
  gemm_splitk<8><<<dim3(32, 8), 512, 0, stream>>>(fc6, W2, Cp, 4096, 128);
  reduce_bias_relu<<<1024, 256, 0, stream>>>(Cp, b2, fc7, 8);
  heads_kernel<<<256, 512, 0, stream>>>(fc7, Wloc, bloc, Wsc, bsc, out);
}

// Round 8
// 409.407 us; speedup vs baseline: 2.2174x; 1.0047x over previous
//
#include <hip/hip_runtime.h>
#include <hip/hip_bf16.h>

typedef unsigned int u32;
typedef unsigned short u16;
typedef __attribute__((ext_vector_type(8))) short bf16x8;
typedef __attribute__((ext_vector_type(4))) float f32x4;
typedef __attribute__((ext_vector_type(4))) u32 u32x4;
typedef __attribute__((ext_vector_type(2))) u32 u32x2;

__device__ __forceinline__ u16 f2b(float f) {
  u32 x = __builtin_bit_cast(u32, f);
  x = (x + 0x7FFFu + ((x >> 16) & 1u)) >> 16;  // RNE
  return (u16)x;
}
__device__ __forceinline__ float b2f(u16 h) {
  return __builtin_bit_cast(float, ((u32)h) << 16);
}

// global -> LDS direct DMA, 16B per lane (no destination registers).
__device__ __forceinline__ void gld_lds16(const u16* g, u16* l) {
  __builtin_amdgcn_global_load_lds(
      (const __attribute__((address_space(1))) u32*)g,
      (__attribute__((address_space(3))) u32*)l, 16, 0, 0);
}

// ---------- 1. transpose fm (512, 1444) -> fmT (1444, 512) ----------
__global__ void transpose_fm(const float* __restrict__ fm, float* __restrict__ fmT) {
  __shared__ float tile[32][33];
  int pb = blockIdx.x * 32, cb = blockIdx.y * 32;
  int tx = threadIdx.x, ty = threadIdx.y;  // block (32,8)
#pragma unroll
  for (int i = 0; i < 4; ++i) {
    int c = cb + ty + i * 8;
    int p = pb + tx;
    tile[ty + i * 8][tx] = (p < 1444) ? fm[c * 1444 + p] : 0.f;
  }
  __syncthreads();
#pragma unroll
  for (int i = 0; i < 4; ++i) {
    int p = pb + ty + i * 8;
    int c = cb + tx;
    if (p < 1444) fmT[p * 512 + c] = tile[tx][ty + i * 8];
  }
}

// ---------- 2. RoI adaptive max pool -> pooled bf16 [256][25088] ----------
__global__ void roi_pool(const float* __restrict__ fmT,
                         const float* __restrict__ rois,
                         u16* __restrict__ pooled) {
  int n = blockIdx.x;
  int c = blockIdx.y * 256 + threadIdx.x;  // 0..511
  const float* rp = rois + n * 4;
  int y0 = (int)(rp[0] * 0.0625f);
  int x0 = (int)(rp[1] * 0.0625f);
  int y2 = (int)(rp[2] * 0.0625f);
  int x2 = (int)(rp[3] * 0.0625f);
  int h = y2 - y0 + 1;
  int w = x2 - x0 + 1;
  int hsA[7], hlA[7], wsA[7], wlA[7];
#pragma unroll
  for (int i = 0; i < 7; ++i) {
    hsA[i] = (i * h) / 7;
    hlA[i] = ((i + 1) * h + 6) / 7 - hsA[i];
    wsA[i] = (i * w) / 7;
    wlA[i] = ((i + 1) * w + 6) / 7 - wsA[i];
  }
  const float* fp = fmT + c;
  u16* op = pooled + (size_t)n * 25088 + (size_t)c * 49;
  for (int i = 0; i < 7; ++i) {
    int yb = y0 + hsA[i];
    for (int j = 0; j < 7; ++j) {
      int xb = x0 + wsA[j];
      float m = -3.0e38f;
      for (int yy = 0; yy < hlA[i]; ++yy) {
        int y = yb + yy; if (y > 37) y = 37;
        const float* rowp = fp + (size_t)(y * 38) * 512;
        for (int xx = 0; xx < wlA[j]; ++xx) {
          int x = xb + xx; if (x > 37) x = 37;
          m = fmaxf(m, rowp[(size_t)x * 512]);
        }
      }
      op[i * 7 + j] = f2b(m);
    }
  }
}

// ---------- 3. split-K GEMM, tile 256(full-M) x 128, BK=32 ----------
// A via global_load_lds (source-swizzled, linear LDS dest); B via E/O 2-deep
// register prefetch; raw barrier with hand-counted vmcnt(8).
// XCD-chunked block swizzle: each XCD gets a CONTIGUOUS id chunk -> the ~2
// distinct A k-slices it hosts (2x918KB) fit its 4MB L2 (vs 14 slices = 12.8MB
// thrash under default round-robin). Requires nwg % 8 == 0 (448, 256: both ok).
#define BK 32
template <int NS>
__global__ __launch_bounds__(512, 4) void gemm_splitk(
    const u16* __restrict__ A, const float* __restrict__ B,
    float* __restrict__ Cp, int lda, int steps_total) {
  const int N = 4096;
  // --- XCD-chunked swizzle (bijective since nwg%8==0; HW assigns wg i -> XCD i%8)
  int wg = blockIdx.x + gridDim.x * blockIdx.y;
  int chunk = (gridDim.x * gridDim.y) >> 3;
  int swz = (wg & 7) * chunk + (wg >> 3);
  int nt = swz & 31;   // gridDim.x == 32 always here
  int ks = swz >> 5;

  int n0 = nt * 128;
  int nsteps = steps_total / NS;  // exact, even, >= 4
  int k0 = ks * nsteps * BK;

  // sA: linear [256][32] bf16 (glld dest must be linear); conflict-freedom via
  // source-side chunk swizzle cg = cs ^ ((row>>1)&3), same xor on read side.
  __shared__ __align__(16) u16 sA[2][256 * 32];  // 32768 B
  __shared__ __align__(16) u16 sB[2][128 * 40];  // 20480 B (80B-padded rows)

  int t = threadIdx.x;
  int lane = t & 63;
  int wid = t >> 6;
  int wm = wid >> 1, wn = wid & 1;  // wave = 64x64 at (wm*64, wn*64)
  int l4 = lane >> 4, lm = lane & 15;

  // --- A glld: issue i covers rows wid*32+i*16..+16; lane l -> row +l/4,
  // slot l&3 holds global chunk (l&3)^((row>>1)&3) = (l&3)^((l>>3)&3).
  int acg = (lane & 3) ^ ((lane >> 3) & 3);
  const u16* gA0 = A + (size_t)(wid * 32 + (lane >> 2)) * lda + k0 + acg * 8;
  const u16* gA1 = gA0 + (size_t)16 * lda;
  int ldsAoff0 = wid * 1024;        // u16 elems
  int ldsAoff1 = wid * 1024 + 512;

  // --- B staging: 8 strided f32 loads -> pack bf16 -> 1 ds_write_b128
  int nB = t & 127, kg = t >> 7;  // col, 8-k group (kg 0..3)
  const float* gB = B + (size_t)(k0 + kg * 8) * N + n0 + nB;

  f32x4 acc[4][4];
#pragma unroll
  for (int i = 0; i < 4; ++i)
#pragma unroll
    for (int j = 0; j < 4; ++j) acc[i][j] = (f32x4)(0.f);

  float eb[8], ob[8];  // E/O register sets for B

#define GLLD(S, BUF)                                       \
  do {                                                     \
    gld_lds16(gA0 + (size_t)(S) * BK, &sA[BUF][ldsAoff0]); \
    gld_lds16(gA1 + (size_t)(S) * BK, &sA[BUF][ldsAoff1]); \
    __builtin_amdgcn_sched_barrier(0);                     \
  } while (0)

#define LOADB(S, RB)                                  \
  do {                                                \
    const float* pb_ = gB + (size_t)(S) * BK * N;     \
    _Pragma("unroll")                                 \
    for (int i_ = 0; i_ < 8; ++i_) RB[i_] = pb_[(size_t)i_ * N]; \
  } while (0)

#define STOREB(BUF, RB)                                             \
  do {                                                              \
    u32x4 bw_;                                                      \
    bw_[0] = (u32)f2b(RB[0]) | ((u32)f2b(RB[1]) << 16);             \
    bw_[1] = (u32)f2b(RB[2]) | ((u32)f2b(RB[3]) << 16);             \
    bw_[2] = (u32)f2b(RB[4]) | ((u32)f2b(RB[5]) << 16);             \
    bw_[3] = (u32)f2b(RB[6]) | ((u32)f2b(RB[7]) << 16);             \
    *(u32x4*)&sB[BUF][nB * 40 + kg * 8] = bw_;                      \
  } while (0)

#define COMPUTE(BUF)                                                         \
  do {                                                                       \
    int sig_ = (lm >> 1) & 3;                                                \
    const u16* pa0_ = &sA[BUF][(wm * 64 + lm) * 32 + ((l4 ^ sig_) * 8)];     \
    const u16* pb0_ = &sB[BUF][(wn * 64 + lm) * 40 + l4 * 8];                \
    bf16x8 af_[4], bf_[4];                                                   \
    _Pragma("unroll")                                                        \
    for (int m_ = 0; m_ < 4; ++m_) af_[m_] = *(const bf16x8*)(pa0_ + m_ * 16 * 32); \
    _Pragma("unroll")                                                        \
    for (int n_ = 0; n_ < 4; ++n_) bf_[n_] = *(const bf16x8*)(pb0_ + n_ * 16 * 40); \
    _Pragma("unroll")                                                        \
    for (int m_ = 0; m_ < 4; ++m_)                                           \
      _Pragma("unroll")                                                      \
      for (int n_ = 0; n_ < 4; ++n_)                                         \
        acc[m_][n_] = __builtin_amdgcn_mfma_f32_16x16x32_bf16(af_[m_], bf_[n_], acc[m_][n_], 0, 0, 0); \
  } while (0)

#define BARV(NVM)                                                      \
  do {                                                                 \
    asm volatile("s_waitcnt vmcnt(" #NVM ") lgkmcnt(0)" ::: "memory"); \
    __builtin_amdgcn_sched_barrier(0);                                 \
    __builtin_amdgcn_s_barrier();                                      \
    __builtin_amdgcn_sched_barrier(0);                                 \
  } while (0)

  // prologue
  GLLD(0, 0);
  LOADB(0, eb);
  LOADB(1, ob);
  STOREB(0, eb);  // dep-wait retires glld(0)+E; O stays in flight
  asm volatile("s_waitcnt lgkmcnt(0)" ::: "memory");
  __builtin_amdgcn_sched_barrier(0);
  __builtin_amdgcn_s_barrier();
  __builtin_amdgcn_sched_barrier(0);

  // invariant at loop top: buf0 = tile s staged; O = B(s+1); E free.
  for (int s = 0; s + 3 < nsteps; s += 2) {
    GLLD(s + 1, 1);
    LOADB(s + 2, eb);
    COMPUTE(0);
    STOREB(1, ob);   // dep-waits O only; E's 8 loads in flight
    BARV(8);         // glld retired; E survives the barrier

    GLLD(s + 2, 0);
    LOADB(s + 3, ob);
    COMPUTE(1);
    STOREB(0, eb);
    BARV(8);
  }
  // tail: tiles nsteps-2 (buf0), nsteps-1; O = B(nsteps-1)
  GLLD(nsteps - 1, 1);
  COMPUTE(0);
  STOREB(1, ob);
  BARV(0);
  COMPUTE(1);

  // epilogue: partial C [ks][256][4096]
#pragma unroll
  for (int m = 0; m < 4; ++m) {
#pragma unroll
    for (int n = 0; n < 4; ++n) {
      int grow = wm * 64 + m * 16 + l4 * 4;
      int gcol = n0 + wn * 64 + n * 16 + lm;
      float* cp = Cp + ((size_t)(ks * 256 + grow)) * 4096 + gcol;
#pragma unroll
      for (int r = 0; r < 4; ++r) cp[(size_t)r * 4096] = acc[m][n][r];
    }
  }
#undef GLLD
#undef LOADB
#undef STOREB
#undef COMPUTE
#undef BARV
}

// ---------- 4. reduce split-K partials + bias + relu -> bf16 (vec4) ----------
__global__ void reduce_bias_relu(const float* __restrict__ Cp,
                                 const float* __restrict__ bias,
                                 u16* __restrict__ outbf, int nsplit) {
  int idx = (blockIdx.x * 256 + threadIdx.x) * 4;  // 256*4096 total elems
  f32x4 s = *(const f32x4*)&bias[idx & 4095];
  for (int k = 0; k < nsplit; ++k) {
    f32x4 v = *(const f32x4*)&Cp[(size_t)k * 1048576 + idx];
#pragma unroll
    for (int j = 0; j < 4; ++j) s[j] += v[j];
  }
  u32x2 o;
  o[0] = (u32)f2b(fmaxf(s[0], 0.f)) | ((u32)f2b(fmaxf(s[1], 0.f)) << 16);
  o[1] = (u32)f2b(fmaxf(s[2], 0.f)) | ((u32)f2b(fmaxf(s[3], 0.f)) << 16);
  *(u32x2*)&outbf[idx] = o;
}

// ---------- 5. heads: one roi per block (256 blocks) ----------
__global__ __launch_bounds__(512) void heads_kernel(
    const u16* __restrict__ fc7,
    const float* __restrict__ Wloc, const float* __restrict__ bloc,
    const float* __restrict__ Wsc, const float* __restrict__ bsc,
    float* __restrict__ out) {
  int t = threadIdx.x;
  int c = t & 127, sl = t >> 7;  // 105 active cols, 4 k-slices
  int r = blockIdx.x;
  const u16* f0 = fc7 + (size_t)r * 4096;
  float acc = 0.f;
  if (c < 105) {
    int kb = sl * 1024;
#pragma unroll 4
    for (int k = kb; k < kb + 1024; ++k) {
      float wv = (c < 84) ? Wloc[(size_t)k * 84 + c] : Wsc[(size_t)k * 21 + (c - 84)];
      acc += b2f(f0[k]) * wv;
    }
  }
  __shared__ float red[4][128];
  red[sl][c] = acc;
  __syncthreads();
  if (sl == 0 && c < 105) {
    float s = red[0][c] + red[1][c] + red[2][c] + red[3][c];
    if (c < 84) out[(size_t)r * 84 + c] = s + bloc[c];
    else out[21504 + (size_t)r * 21 + (c - 84)] = s + bsc[c - 84];
  }
}

extern "C" void kernel_launch(void* const* d_in, const int* in_sizes, int n_in,
                              void* d_out, int out_size, void* d_ws, size_t ws_size,
                              hipStream_t stream) {
  const float* fm   = (const float*)d_in[0];
  const float* rois = (const float*)d_in[1];
  const float* W1   = (const float*)d_in[2];
  const float* b1   = (const float*)d_in[3];
  const float* W2   = (const float*)d_in[4];
  const float* b2   = (const float*)d_in[5];
  const float* Wloc = (const float*)d_in[6];
  const float* bloc = (const float*)d_in[7];
  const float* Wsc  = (const float*)d_in[8];
  const float* bsc  = (const float*)d_in[9];
  float* out = (float*)d_out;

  char* ws = (char*)d_ws;
  float* fmT   = (float*)(ws);               // 1444*512*4   = 2,957,312 B
  u16*  pooled = (u16*)(ws + 2957312);       // 256*25088*2  = 12,845,056 B
  u16*  fc6    = (u16*)(ws + 15802368);      // 256*4096*2   = 2,097,152 B
  u16*  fc7    = (u16*)(ws + 17899520);      // 256*4096*2   = 2,097,152 B
  float* Cp    = (float*)(ws + 19996672);    // 14*256*4096*4 = 58,720,256 B (reused)

  transpose_fm<<<dim3(46, 16), dim3(32, 8), 0, stream>>>(fm, fmT);
  roi_pool<<<dim3(256, 2), 256, 0, stream>>>(fmT, rois, pooled);
  // GEMM1: 784 k-steps = 14 splits x 56 steps (even); 32 n-tiles of 128
  gemm_splitk<14><<<dim3(32, 14), 512, 0, stream>>>(pooled, W1, Cp, 25088, 784);
  reduce_bias_relu<<<1024, 256, 0, stream>>>(Cp, b1, fc6, 14);
  // GEMM2: 128 k-steps = 8 splits x 16 steps (even)
  gemm_splitk<8><<<dim3(32, 8), 512, 0, stream>>>(fc6, W2, Cp, 4096, 128);
  reduce_bias_relu<<<1024, 256, 0, stream>>>(Cp, b2, fc7, 8);
  heads_kernel<<<256, 512, 0, stream>>>(fc7, Wloc, bloc, Wsc, bsc, out);
}

// Round 9
// 330.550 us; speedup vs baseline: 2.7464x; 1.2386x over previous
//
#include <hip/hip_runtime.h>
#include <hip/hip_bf16.h>

typedef unsigned int u32;
typedef unsigned short u16;
typedef __attribute__((ext_vector_type(8))) short bf16x8;
typedef __attribute__((ext_vector_type(4))) float f32x4;
typedef __attribute__((ext_vector_type(4))) u32 u32x4;
typedef __attribute__((ext_vector_type(2))) u32 u32x2;

__device__ __forceinline__ u16 f2b(float f) {
  u32 x = __builtin_bit_cast(u32, f);
  x = (x + 0x7FFFu + ((x >> 16) & 1u)) >> 16;  // RNE
  return (u16)x;
}
__device__ __forceinline__ float b2f(u16 h) {
  return __builtin_bit_cast(float, ((u32)h) << 16);
}

// global -> LDS direct DMA, 16B per lane (no destination registers).
__device__ __forceinline__ void gld_lds16(const u16* g, u16* l) {
  __builtin_amdgcn_global_load_lds(
      (const __attribute__((address_space(1))) u32*)g,
      (__attribute__((address_space(3))) u32*)l, 16, 0, 0);
}

// ---------- 1. transpose fm (512, 1444) -> fmT (1444, 512) ----------
__global__ void transpose_fm(const float* __restrict__ fm, float* __restrict__ fmT) {
  __shared__ float tile[32][33];
  int pb = blockIdx.x * 32, cb = blockIdx.y * 32;
  int tx = threadIdx.x, ty = threadIdx.y;  // block (32,8)
#pragma unroll
  for (int i = 0; i < 4; ++i) {
    int c = cb + ty + i * 8;
    int p = pb + tx;
    tile[ty + i * 8][tx] = (p < 1444) ? fm[c * 1444 + p] : 0.f;
  }
  __syncthreads();
#pragma unroll
  for (int i = 0; i < 4; ++i) {
    int p = pb + ty + i * 8;
    int c = cb + tx;
    if (p < 1444) fmT[p * 512 + c] = tile[tx][ty + i * 8];
  }
}

// ---------- 2. RoI adaptive max pool -> pooled bf16 [256][25088] ----------
// Grid (256 rois, 7 bin-rows), 512 threads = all channels. Each thread computes
// the 7 bins of its (roi, row) for one channel: ~46 coalesced L2-hit loads.
// 1792 blocks x 8 waves = 14 waves/SIMD queue -> latency hidden by TLP
// (old layout: 2 waves/SIMD, latency-bound).
__global__ __launch_bounds__(512) void roi_pool(const float* __restrict__ fmT,
                                                const float* __restrict__ rois,
                                                u16* __restrict__ pooled) {
  int n = blockIdx.x;
  int i = blockIdx.y;        // bin row 0..6
  int c = threadIdx.x;       // 0..511
  const float* rp = rois + n * 4;
  int y0 = (int)(rp[0] * 0.0625f);
  int x0 = (int)(rp[1] * 0.0625f);
  int y2 = (int)(rp[2] * 0.0625f);
  int x2 = (int)(rp[3] * 0.0625f);
  int h = y2 - y0 + 1;
  int w = x2 - x0 + 1;
  int hs = (i * h) / 7;
  int hl = ((i + 1) * h + 6) / 7 - hs;
  int wsA[7], wlA[7];
#pragma unroll
  for (int j = 0; j < 7; ++j) {
    wsA[j] = (j * w) / 7;
    wlA[j] = ((j + 1) * w + 6) / 7 - wsA[j];
  }
  const float* fp = fmT + c;
  u16* op = pooled + (size_t)n * 25088 + (size_t)c * 49 + i * 7;
  int yb = y0 + hs;
  float m[7];
#pragma unroll
  for (int j = 0; j < 7; ++j) m[j] = -3.0e38f;
  for (int yy = 0; yy < hl; ++yy) {
    int y = yb + yy; if (y > 37) y = 37;
    const float* rowp = fp + (size_t)(y * 38) * 512;
    for (int j = 0; j < 7; ++j) {
      int xb = x0 + wsA[j];
      for (int xx = 0; xx < wlA[j]; ++xx) {
        int x = xb + xx; if (x > 37) x = 37;
        m[j] = fmaxf(m[j], rowp[(size_t)x * 512]);
      }
    }
  }
#pragma unroll
  for (int j = 0; j < 7; ++j) op[j] = f2b(m[j]);
}

// ---------- 3. split-K GEMM, tile 256(full-M) x 128, BK=32 ----------
// A via global_load_lds (source-swizzled, linear LDS dest); B via E/O 2-deep
// register prefetch; raw barrier with hand-counted vmcnt(8).
#define BK 32
template <int NS>
__global__ __launch_bounds__(512, 4) void gemm_splitk(
    const u16* __restrict__ A, const float* __restrict__ B,
    float* __restrict__ Cp, int lda, int steps_total) {
  const int N = 4096;
  // --- XCD-chunked swizzle (bijective since nwg%8==0)
  int wg = blockIdx.x + gridDim.x * blockIdx.y;
  int chunk = (gridDim.x * gridDim.y) >> 3;
  int swz = (wg & 7) * chunk + (wg >> 3);
  int nt = swz & 31;   // gridDim.x == 32 always here
  int ks = swz >> 5;

  int n0 = nt * 128;
  int nsteps = steps_total / NS;  // exact, even, >= 4
  int k0 = ks * nsteps * BK;

  __shared__ __align__(16) u16 sA[2][256 * 32];  // 32768 B (linear for glld)
  __shared__ __align__(16) u16 sB[2][128 * 40];  // 20480 B (80B-padded rows)

  int t = threadIdx.x;
  int lane = t & 63;
  int wid = t >> 6;
  int wm = wid >> 1, wn = wid & 1;  // wave = 64x64 at (wm*64, wn*64)
  int l4 = lane >> 4, lm = lane & 15;

  // A glld source swizzle: slot l&3 holds chunk (l&3)^((l>>3)&3)
  int acg = (lane & 3) ^ ((lane >> 3) & 3);
  const u16* gA0 = A + (size_t)(wid * 32 + (lane >> 2)) * lda + k0 + acg * 8;
  const u16* gA1 = gA0 + (size_t)16 * lda;
  int ldsAoff0 = wid * 1024;
  int ldsAoff1 = wid * 1024 + 512;

  int nB = t & 127, kg = t >> 7;  // B staging: col, 8-k group
  const float* gB = B + (size_t)(k0 + kg * 8) * N + n0 + nB;

  f32x4 acc[4][4];
#pragma unroll
  for (int i = 0; i < 4; ++i)
#pragma unroll
    for (int j = 0; j < 4; ++j) acc[i][j] = (f32x4)(0.f);

  float eb[8], ob[8];  // E/O register sets for B

#define GLLD(S, BUF)                                       \
  do {                                                     \
    gld_lds16(gA0 + (size_t)(S) * BK, &sA[BUF][ldsAoff0]); \
    gld_lds16(gA1 + (size_t)(S) * BK, &sA[BUF][ldsAoff1]); \
    __builtin_amdgcn_sched_barrier(0);                     \
  } while (0)

#define LOADB(S, RB)                                  \
  do {                                                \
    const float* pb_ = gB + (size_t)(S) * BK * N;     \
    _Pragma("unroll")                                 \
    for (int i_ = 0; i_ < 8; ++i_) RB[i_] = pb_[(size_t)i_ * N]; \
  } while (0)

#define STOREB(BUF, RB)                                             \
  do {                                                              \
    u32x4 bw_;                                                      \
    bw_[0] = (u32)f2b(RB[0]) | ((u32)f2b(RB[1]) << 16);             \
    bw_[1] = (u32)f2b(RB[2]) | ((u32)f2b(RB[3]) << 16);             \
    bw_[2] = (u32)f2b(RB[4]) | ((u32)f2b(RB[5]) << 16);             \
    bw_[3] = (u32)f2b(RB[6]) | ((u32)f2b(RB[7]) << 16);             \
    *(u32x4*)&sB[BUF][nB * 40 + kg * 8] = bw_;                      \
  } while (0)

#define COMPUTE(BUF)                                                         \
  do {                                                                       \
    int sig_ = (lm >> 1) & 3;                                                \
    const u16* pa0_ = &sA[BUF][(wm * 64 + lm) * 32 + ((l4 ^ sig_) * 8)];     \
    const u16* pb0_ = &sB[BUF][(wn * 64 + lm) * 40 + l4 * 8];                \
    bf16x8 af_[4], bf_[4];                                                   \
    _Pragma("unroll")                                                        \
    for (int m_ = 0; m_ < 4; ++m_) af_[m_] = *(const bf16x8*)(pa0_ + m_ * 16 * 32); \
    _Pragma("unroll")                                                        \
    for (int n_ = 0; n_ < 4; ++n_) bf_[n_] = *(const bf16x8*)(pb0_ + n_ * 16 * 40); \
    _Pragma("unroll")                                                        \
    for (int m_ = 0; m_ < 4; ++m_)                                           \
      _Pragma("unroll")                                                      \
      for (int n_ = 0; n_ < 4; ++n_)                                         \
        acc[m_][n_] = __builtin_amdgcn_mfma_f32_16x16x32_bf16(af_[m_], bf_[n_], acc[m_][n_], 0, 0, 0); \
  } while (0)

#define BARV(NVM)                                                      \
  do {                                                                 \
    asm volatile("s_waitcnt vmcnt(" #NVM ") lgkmcnt(0)" ::: "memory"); \
    __builtin_amdgcn_sched_barrier(0);                                 \
    __builtin_amdgcn_s_barrier();                                      \
    __builtin_amdgcn_sched_barrier(0);                                 \
  } while (0)

  // prologue
  GLLD(0, 0);
  LOADB(0, eb);
  LOADB(1, ob);
  STOREB(0, eb);  // dep-wait retires glld(0)+E; O stays in flight
  asm volatile("s_waitcnt lgkmcnt(0)" ::: "memory");
  __builtin_amdgcn_sched_barrier(0);
  __builtin_amdgcn_s_barrier();
  __builtin_amdgcn_sched_barrier(0);

  // invariant at loop top: buf0 = tile s staged; O = B(s+1); E free.
  for (int s = 0; s + 3 < nsteps; s += 2) {
    GLLD(s + 1, 1);
    LOADB(s + 2, eb);
    COMPUTE(0);
    STOREB(1, ob);   // dep-waits O only; E's 8 loads in flight
    BARV(8);         // glld retired; E survives the barrier

    GLLD(s + 2, 0);
    LOADB(s + 3, ob);
    COMPUTE(1);
    STOREB(0, eb);
    BARV(8);
  }
  // tail: tiles nsteps-2 (buf0), nsteps-1; O = B(nsteps-1)
  GLLD(nsteps - 1, 1);
  COMPUTE(0);
  STOREB(1, ob);
  BARV(0);
  COMPUTE(1);

  // epilogue: partial C [ks][256][4096]
#pragma unroll
  for (int m = 0; m < 4; ++m) {
#pragma unroll
    for (int n = 0; n < 4; ++n) {
      int grow = wm * 64 + m * 16 + l4 * 4;
      int gcol = n0 + wn * 64 + n * 16 + lm;
      float* cp = Cp + ((size_t)(ks * 256 + grow)) * 4096 + gcol;
#pragma unroll
      for (int r = 0; r < 4; ++r) cp[(size_t)r * 4096] = acc[m][n][r];
    }
  }
#undef GLLD
#undef LOADB
#undef STOREB
#undef COMPUTE
#undef BARV
}

// ---------- 4. reduce split-K partials + bias + relu -> bf16 (vec4) ----------
__global__ void reduce_bias_relu(const float* __restrict__ Cp,
                                 const float* __restrict__ bias,
                                 u16* __restrict__ outbf, int nsplit) {
  int idx = (blockIdx.x * 256 + threadIdx.x) * 4;  // 256*4096 total elems
  f32x4 s = *(const f32x4*)&bias[idx & 4095];
  for (int k = 0; k < nsplit; ++k) {
    f32x4 v = *(const f32x4*)&Cp[(size_t)k * 1048576 + idx];
#pragma unroll
    for (int j = 0; j < 4; ++j) s[j] += v[j];
  }
  u32x2 o;
  o[0] = (u32)f2b(fmaxf(s[0], 0.f)) | ((u32)f2b(fmaxf(s[1], 0.f)) << 16);
  o[1] = (u32)f2b(fmaxf(s[2], 0.f)) | ((u32)f2b(fmaxf(s[3], 0.f)) << 16);
  *(u32x2*)&outbf[idx] = o;
}

// ---------- 5. heads: one roi per block (256 blocks) ----------
__global__ __launch_bounds__(512) void heads_kernel(
    const u16* __restrict__ fc7,
    const float* __restrict__ Wloc, const float* __restrict__ bloc,
    const float* __restrict__ Wsc, const float* __restrict__ bsc,
    float* __restrict__ out) {
  int t = threadIdx.x;
  int c = t & 127, sl = t >> 7;  // 105 active cols, 4 k-slices
  int r = blockIdx.x;
  const u16* f0 = fc7 + (size_t)r * 4096;
  float acc = 0.f;
  if (c < 105) {
    int kb = sl * 1024;
#pragma unroll 4
    for (int k = kb; k < kb + 1024; ++k) {
      float wv = (c < 84) ? Wloc[(size_t)k * 84 + c] : Wsc[(size_t)k * 21 + (c - 84)];
      acc += b2f(f0[k]) * wv;
    }
  }
  __shared__ float red[4][128];
  red[sl][c] = acc;
  __syncthreads();
  if (sl == 0 && c < 105) {
    float s = red[0][c] + red[1][c] + red[2][c] + red[3][c];
    if (c < 84) out[(size_t)r * 84 + c] = s + bloc[c];
    else out[21504 + (size_t)r * 21 + (c - 84)] = s + bsc[c - 84];
  }
}

extern "C" void kernel_launch(void* const* d_in, const int* in_sizes, int n_in,
                              void* d_out, int out_size, void* d_ws, size_t ws_size,
                              hipStream_t stream) {
  const float* fm   = (const float*)d_in[0];
  const float* rois = (const float*)d_in[1];
  const float* W1   = (const float*)d_in[2];
  const float* b1   = (const float*)d_in[3];
  const float* W2   = (const float*)d_in[4];
  const float* b2   = (const float*)d_in[5];
  const float* Wloc = (const float*)d_in[6];
  const float* bloc = (const float*)d_in[7];
  const float* Wsc  = (const float*)d_in[8];
  const float* bsc  = (const float*)d_in[9];
  float* out = (float*)d_out;

  char* ws = (char*)d_ws;
  float* fmT   = (float*)(ws);               // 1444*512*4   = 2,957,312 B
  u16*  pooled = (u16*)(ws + 2957312);       // 256*25088*2  = 12,845,056 B
  u16*  fc6    = (u16*)(ws + 15802368);      // 256*4096*2   = 2,097,152 B
  u16*  fc7    = (u16*)(ws + 17899520);      // 256*4096*2   = 2,097,152 B
  float* Cp    = (float*)(ws + 19996672);    // 14*256*4096*4 = 58,720,256 B (reused)

  transpose_fm<<<dim3(46, 16), dim3(32, 8), 0, stream>>>(fm, fmT);
  roi_pool<<<dim3(256, 7), 512, 0, stream>>>(fmT, rois, pooled);
  // GEMM1: 784 k-steps = 14 splits x 56 steps (even); 32 n-tiles of 128
  gemm_splitk<14><<<dim3(32, 14), 512, 0, stream>>>(pooled, W1, Cp, 25088, 784);
  reduce_bias_relu<<<1024, 256, 0, stream>>>(Cp, b1, fc6, 14);
  // GEMM2: 128 k-steps = 8 splits x 16 steps (even)
  gemm_splitk<8><<<dim3(32, 8), 512, 0, stream>>>(fc6, W2, Cp, 4096, 128);
  reduce_bias_relu<<<1024, 256, 0, stream>>>(Cp, b2, fc7, 8);
  heads_kernel<<<256, 512, 0, stream>>>(fc7, Wloc, bloc, Wsc, bsc, out);
}

// Round 10
// 317.115 us; speedup vs baseline: 2.8628x; 1.0424x over previous
//
#include <hip/hip_runtime.h>
#include <hip/hip_bf16.h>

typedef unsigned int u32;
typedef unsigned short u16;
typedef __attribute__((ext_vector_type(8))) short bf16x8;
typedef __attribute__((ext_vector_type(4))) float f32x4;
typedef __attribute__((ext_vector_type(4))) u32 u32x4;
typedef __attribute__((ext_vector_type(2))) u32 u32x2;
typedef __attribute__((ext_vector_type(8))) u16 u16x8;

__device__ __forceinline__ u16 f2b(float f) {
  u32 x = __builtin_bit_cast(u32, f);
  x = (x + 0x7FFFu + ((x >> 16) & 1u)) >> 16;  // RNE
  return (u16)x;
}
__device__ __forceinline__ float b2f(u16 h) {
  return __builtin_bit_cast(float, ((u32)h) << 16);
}

// global -> LDS direct DMA, 16B per lane (no destination registers).
__device__ __forceinline__ void gld_lds16(const u16* g, u16* l) {
  __builtin_amdgcn_global_load_lds(
      (const __attribute__((address_space(1))) u32*)g,
      (__attribute__((address_space(3))) u32*)l, 16, 0, 0);
}

// ---------- 1. transpose fm (512, 1444) -> fmT (1444, 512) ----------
__global__ void transpose_fm(const float* __restrict__ fm, float* __restrict__ fmT) {
  __shared__ float tile[32][33];
  int pb = blockIdx.x * 32, cb = blockIdx.y * 32;
  int tx = threadIdx.x, ty = threadIdx.y;  // block (32,8)
#pragma unroll
  for (int i = 0; i < 4; ++i) {
    int c = cb + ty + i * 8;
    int p = pb + tx;
    tile[ty + i * 8][tx] = (p < 1444) ? fm[c * 1444 + p] : 0.f;
  }
  __syncthreads();
#pragma unroll
  for (int i = 0; i < 4; ++i) {
    int p = pb + ty + i * 8;
    int c = cb + tx;
    if (p < 1444) fmT[p * 512 + c] = tile[tx][ty + i * 8];
  }
}

// ---------- 2. RoI adaptive max pool -> pooled bf16 [256][25088] ----------
// Grid (256 rois, 7 bin-rows), 512 threads = all channels (TLP-rich: R9 lever).
__global__ __launch_bounds__(512) void roi_pool(const float* __restrict__ fmT,
                                                const float* __restrict__ rois,
                                                u16* __restrict__ pooled) {
  int n = blockIdx.x;
  int i = blockIdx.y;        // bin row 0..6
  int c = threadIdx.x;       // 0..511
  const float* rp = rois + n * 4;
  int y0 = (int)(rp[0] * 0.0625f);
  int x0 = (int)(rp[1] * 0.0625f);
  int y2 = (int)(rp[2] * 0.0625f);
  int x2 = (int)(rp[3] * 0.0625f);
  int h = y2 - y0 + 1;
  int w = x2 - x0 + 1;
  int hs = (i * h) / 7;
  int hl = ((i + 1) * h + 6) / 7 - hs;
  int wsA[7], wlA[7];
#pragma unroll
  for (int j = 0; j < 7; ++j) {
    wsA[j] = (j * w) / 7;
    wlA[j] = ((j + 1) * w + 6) / 7 - wsA[j];
  }
  const float* fp = fmT + c;
  u16* op = pooled + (size_t)n * 25088 + (size_t)c * 49 + i * 7;
  int yb = y0 + hs;
  float m[7];
#pragma unroll
  for (int j = 0; j < 7; ++j) m[j] = -3.0e38f;
  for (int yy = 0; yy < hl; ++yy) {
    int y = yb + yy; if (y > 37) y = 37;
    const float* rowp = fp + (size_t)(y * 38) * 512;
    for (int j = 0; j < 7; ++j) {
      int xb = x0 + wsA[j];
      for (int xx = 0; xx < wlA[j]; ++xx) {
        int x = xb + xx; if (x > 37) x = 37;
        m[j] = fmaxf(m[j], rowp[(size_t)x * 512]);
      }
    }
  }
#pragma unroll
  for (int j = 0; j < 7; ++j) op[j] = f2b(m[j]);
}

// ---------- 3. split-K GEMM, tile 256(full-M) x 128, BK=32; bf16 partials ----------
// A via global_load_lds (source-swizzled, linear LDS dest); B via E/O 2-deep
// register prefetch; raw barrier with hand-counted vmcnt(8).
#define BK 32
template <int NS>
__global__ __launch_bounds__(512, 4) void gemm_splitk(
    const u16* __restrict__ A, const float* __restrict__ B,
    u16* __restrict__ Cp16, int lda, int steps_total) {
  const int N = 4096;
  // --- XCD-chunked swizzle (bijective since nwg%8==0)
  int wg = blockIdx.x + gridDim.x * blockIdx.y;
  int chunk = (gridDim.x * gridDim.y) >> 3;
  int swz = (wg & 7) * chunk + (wg >> 3);
  int nt = swz & 31;   // gridDim.x == 32 always here
  int ks = swz >> 5;

  int n0 = nt * 128;
  int nsteps = steps_total / NS;  // exact, even, >= 4
  int k0 = ks * nsteps * BK;

  __shared__ __align__(16) u16 sA[2][256 * 32];  // 32768 B (linear for glld)
  __shared__ __align__(16) u16 sB[2][128 * 40];  // 20480 B (80B-padded rows)

  int t = threadIdx.x;
  int lane = t & 63;
  int wid = t >> 6;
  int wm = wid >> 1, wn = wid & 1;  // wave = 64x64 at (wm*64, wn*64)
  int l4 = lane >> 4, lm = lane & 15;

  // A glld source swizzle: slot l&3 holds chunk (l&3)^((l>>3)&3)
  int acg = (lane & 3) ^ ((lane >> 3) & 3);
  const u16* gA0 = A + (size_t)(wid * 32 + (lane >> 2)) * lda + k0 + acg * 8;
  const u16* gA1 = gA0 + (size_t)16 * lda;
  int ldsAoff0 = wid * 1024;
  int ldsAoff1 = wid * 1024 + 512;

  int nB = t & 127, kg = t >> 7;  // B staging: col, 8-k group
  const float* gB = B + (size_t)(k0 + kg * 8) * N + n0 + nB;

  f32x4 acc[4][4];
#pragma unroll
  for (int i = 0; i < 4; ++i)
#pragma unroll
    for (int j = 0; j < 4; ++j) acc[i][j] = (f32x4)(0.f);

  float eb[8], ob[8];  // E/O register sets for B

#define GLLD(S, BUF)                                       \
  do {                                                     \
    gld_lds16(gA0 + (size_t)(S) * BK, &sA[BUF][ldsAoff0]); \
    gld_lds16(gA1 + (size_t)(S) * BK, &sA[BUF][ldsAoff1]); \
    __builtin_amdgcn_sched_barrier(0);                     \
  } while (0)

#define LOADB(S, RB)                                  \
  do {                                                \
    const float* pb_ = gB + (size_t)(S) * BK * N;     \
    _Pragma("unroll")                                 \
    for (int i_ = 0; i_ < 8; ++i_) RB[i_] = pb_[(size_t)i_ * N]; \
  } while (0)

#define STOREB(BUF, RB)                                             \
  do {                                                              \
    u32x4 bw_;                                                      \
    bw_[0] = (u32)f2b(RB[0]) | ((u32)f2b(RB[1]) << 16);             \
    bw_[1] = (u32)f2b(RB[2]) | ((u32)f2b(RB[3]) << 16);             \
    bw_[2] = (u32)f2b(RB[4]) | ((u32)f2b(RB[5]) << 16);             \
    bw_[3] = (u32)f2b(RB[6]) | ((u32)f2b(RB[7]) << 16);             \
    *(u32x4*)&sB[BUF][nB * 40 + kg * 8] = bw_;                      \
  } while (0)

#define COMPUTE(BUF)                                                         \
  do {                                                                       \
    int sig_ = (lm >> 1) & 3;                                                \
    const u16* pa0_ = &sA[BUF][(wm * 64 + lm) * 32 + ((l4 ^ sig_) * 8)];     \
    const u16* pb0_ = &sB[BUF][(wn * 64 + lm) * 40 + l4 * 8];                \
    bf16x8 af_[4], bf_[4];                                                   \
    _Pragma("unroll")                                                        \
    for (int m_ = 0; m_ < 4; ++m_) af_[m_] = *(const bf16x8*)(pa0_ + m_ * 16 * 32); \
    _Pragma("unroll")                                                        \
    for (int n_ = 0; n_ < 4; ++n_) bf_[n_] = *(const bf16x8*)(pb0_ + n_ * 16 * 40); \
    _Pragma("unroll")                                                        \
    for (int m_ = 0; m_ < 4; ++m_)                                           \
      _Pragma("unroll")                                                      \
      for (int n_ = 0; n_ < 4; ++n_)                                         \
        acc[m_][n_] = __builtin_amdgcn_mfma_f32_16x16x32_bf16(af_[m_], bf_[n_], acc[m_][n_], 0, 0, 0); \
  } while (0)

#define BARV(NVM)                                                      \
  do {                                                                 \
    asm volatile("s_waitcnt vmcnt(" #NVM ") lgkmcnt(0)" ::: "memory"); \
    __builtin_amdgcn_sched_barrier(0);                                 \
    __builtin_amdgcn_s_barrier();                                      \
    __builtin_amdgcn_sched_barrier(0);                                 \
  } while (0)

  // prologue
  GLLD(0, 0);
  LOADB(0, eb);
  LOADB(1, ob);
  STOREB(0, eb);  // dep-wait retires glld(0)+E; O stays in flight
  asm volatile("s_waitcnt lgkmcnt(0)" ::: "memory");
  __builtin_amdgcn_sched_barrier(0);
  __builtin_amdgcn_s_barrier();
  __builtin_amdgcn_sched_barrier(0);

  // invariant at loop top: buf0 = tile s staged; O = B(s+1); E free.
  for (int s = 0; s + 3 < nsteps; s += 2) {
    GLLD(s + 1, 1);
    LOADB(s + 2, eb);
    COMPUTE(0);
    STOREB(1, ob);   // dep-waits O only; E's 8 loads in flight
    BARV(8);         // glld retired; E survives the barrier

    GLLD(s + 2, 0);
    LOADB(s + 3, ob);
    COMPUTE(1);
    STOREB(0, eb);
    BARV(8);
  }
  // tail: tiles nsteps-2 (buf0), nsteps-1; O = B(nsteps-1)
  GLLD(nsteps - 1, 1);
  COMPUTE(0);
  STOREB(1, ob);
  BARV(0);
  COMPUTE(1);

  // epilogue: bf16 partials Cp16[ks][256][4096] (halves split-K traffic)
#pragma unroll
  for (int m = 0; m < 4; ++m) {
#pragma unroll
    for (int n = 0; n < 4; ++n) {
      int grow = wm * 64 + m * 16 + l4 * 4;
      int gcol = n0 + wn * 64 + n * 16 + lm;
      u16* cp = Cp16 + ((size_t)(ks * 256 + grow)) * 4096 + gcol;
#pragma unroll
      for (int r = 0; r < 4; ++r) cp[(size_t)r * 4096] = f2b(acc[m][n][r]);
    }
  }
#undef GLLD
#undef LOADB
#undef STOREB
#undef COMPUTE
#undef BARV
}

// ---------- 4. reduce bf16 split-K partials + bias + relu -> bf16 (vec8) ----------
__global__ void reduce_bias_relu(const u16* __restrict__ Cp16,
                                 const float* __restrict__ bias,
                                 u16* __restrict__ outbf, int nsplit) {
  int idx = (blockIdx.x * 256 + threadIdx.x) * 8;  // 256*4096 total elems
  int bcol = idx & 4095;
  f32x4 b0 = *(const f32x4*)&bias[bcol];
  f32x4 b1 = *(const f32x4*)&bias[bcol + 4];
  float s[8];
#pragma unroll
  for (int j = 0; j < 4; ++j) { s[j] = b0[j]; s[j + 4] = b1[j]; }
  for (int k = 0; k < nsplit; ++k) {
    u16x8 v = *(const u16x8*)&Cp16[(size_t)k * 1048576 + idx];
#pragma unroll
    for (int j = 0; j < 8; ++j) s[j] += b2f(v[j]);
  }
  u32x4 o;
#pragma unroll
  for (int j = 0; j < 4; ++j)
    o[j] = (u32)f2b(fmaxf(s[2 * j], 0.f)) | ((u32)f2b(fmaxf(s[2 * j + 1], 0.f)) << 16);
  *(u32x4*)&outbf[idx] = o;
}

// ---------- 5. heads: one roi per block (256 blocks) ----------
__global__ __launch_bounds__(512) void heads_kernel(
    const u16* __restrict__ fc7,
    const float* __restrict__ Wloc, const float* __restrict__ bloc,
    const float* __restrict__ Wsc, const float* __restrict__ bsc,
    float* __restrict__ out) {
  int t = threadIdx.x;
  int c = t & 127, sl = t >> 7;  // 105 active cols, 4 k-slices
  int r = blockIdx.x;
  const u16* f0 = fc7 + (size_t)r * 4096;
  float acc = 0.f;
  if (c < 105) {
    int kb = sl * 1024;
#pragma unroll 4
    for (int k = kb; k < kb + 1024; ++k) {
      float wv = (c < 84) ? Wloc[(size_t)k * 84 + c] : Wsc[(size_t)k * 21 + (c - 84)];
      acc += b2f(f0[k]) * wv;
    }
  }
  __shared__ float red[4][128];
  red[sl][c] = acc;
  __syncthreads();
  if (sl == 0 && c < 105) {
    float s = red[0][c] + red[1][c] + red[2][c] + red[3][c];
    if (c < 84) out[(size_t)r * 84 + c] = s + bloc[c];
    else out[21504 + (size_t)r * 21 + (c - 84)] = s + bsc[c - 84];
  }
}

extern "C" void kernel_launch(void* const* d_in, const int* in_sizes, int n_in,
                              void* d_out, int out_size, void* d_ws, size_t ws_size,
                              hipStream_t stream) {
  const float* fm   = (const float*)d_in[0];
  const float* rois = (const float*)d_in[1];
  const float* W1   = (const float*)d_in[2];
  const float* b1   = (const float*)d_in[3];
  const float* W2   = (const float*)d_in[4];
  const float* b2   = (const float*)d_in[5];
  const float* Wloc = (const float*)d_in[6];
  const float* bloc = (const float*)d_in[7];
  const float* Wsc  = (const float*)d_in[8];
  const float* bsc  = (const float*)d_in[9];
  float* out = (float*)d_out;

  char* ws = (char*)d_ws;
  float* fmT   = (float*)(ws);               // 1444*512*4   = 2,957,312 B
  u16*  pooled = (u16*)(ws + 2957312);       // 256*25088*2  = 12,845,056 B
  u16*  fc6    = (u16*)(ws + 15802368);      // 256*4096*2   = 2,097,152 B
  u16*  fc7    = (u16*)(ws + 17899520);      // 256*4096*2   = 2,097,152 B
  u16*  Cp16   = (u16*)(ws + 19996672);      // 14*256*4096*2 = 29,360,128 B (reused)

  transpose_fm<<<dim3(46, 16), dim3(32, 8), 0, stream>>>(fm, fmT);
  roi_pool<<<dim3(256, 7), 512, 0, stream>>>(fmT, rois, pooled);
  // GEMM1: 784 k-steps = 14 splits x 56 steps (even); 32 n-tiles of 128
  gemm_splitk<14><<<dim3(32, 14), 512, 0, stream>>>(pooled, W1, Cp16, 25088, 784);
  reduce_bias_relu<<<512, 256, 0, stream>>>(Cp16, b1, fc6, 14);
  // GEMM2: 128 k-steps = 8 splits x 16 steps (even)
  gemm_splitk<8><<<dim3(32, 8), 512, 0, stream>>>(fc6, W2, Cp16, 4096, 128);
  reduce_bias_relu<<<512, 256, 0, stream>>>(Cp16, b2, fc7, 8);
  heads_kernel<<<256, 512, 0, stream>>>(fc7, Wloc, bloc, Wsc, bsc, out);
}